// Round 8
// baseline (3739.753 us; speedup 1.0000x reference)
//
#include <hip/hip_runtime.h>
#include <math.h>

#define HH 2048
#define WW 2048
#define NIMG 4
#define NCH 3
#define PLANES (NIMG*NCH)            // 12
#define PIX (HH*WW)                  // 4194304
#define TOT (PLANES*PIX)             // 50331648
#define W4 (WW/4)                    // 512
#define MED_RANK 25165823u           // floor(0.5*(TOT-1)), method='lower'
#define NREG 32                      // compaction regions
#define REGCAP (TOT/NREG)            // 1572864 keys/region == elements scanned/group

struct GW { float w[7]; };

// ---------------- module-global device state ----------------
// Cross-kernel visibility via kernel-boundary acquire/release (r4/r7-proven).
// Radix split: 12 (top) / 8 (mid) / 12 (low) bits of the monotonic key.
__device__ unsigned g_hist1[4096];   // pass 1: key>>20
__device__ unsigned g_hist2[256];    // pass 2: (key>>12)&0xFF
__device__ unsigned g_hist3[4096];   // pass 3: key&0xFFF
__device__ unsigned g_ctrl[8];       // [0]=b1 [1]=b2 [2]=b3 [3]=rank2 [4]=rank3
__device__ unsigned g_rcount[NREG];  // compacted-survivor counts per region
__device__ float    g_med;

__global__ void zero_state() {
    int t = blockIdx.x * 256 + threadIdx.x;
    if (t < 4096) { g_hist1[t] = 0; g_hist3[t] = 0; }
    if (t < 256)  g_hist2[t] = 0;
    if (t < NREG) g_rcount[t] = 0;
    if (t < 8)    g_ctrl[t] = 0;
    if (t == 0)   g_med = 0.f;
}

// ---------------- Pass A: fused Sobel + horizontal Gaussian [r6-proven] ----
__global__ __launch_bounds__(256) void sobel_gauss_h(const float* __restrict__ x,
                                                     float* __restrict__ Bh, GW g) {
    int w0 = (blockIdx.x * 256 + threadIdx.x) * 4;     // 0..2044
    int h  = blockIdx.y;
    int n  = blockIdx.z;
    const float* xp = x + (size_t)n * PIX;
    const float* p0 = xp + (size_t)(h - 1) * WW;
    const float* p1 = xp + (size_t)h * WW;
    const float* p2 = xp + (size_t)(h + 1) * WW;
    bool has0 = (h > 0), has2 = (h < HH - 1);

    float r0[12], r1[12], r2[12];
    if (w0 >= 4 && w0 <= WW - 8) {          // interior: 9 float4 loads
#pragma unroll
        for (int b = 0; b < 3; b++) {
            int col = w0 - 4 + b * 4;
            float4 v0 = has0 ? *(const float4*)(p0 + col) : make_float4(0, 0, 0, 0);
            float4 v1 = *(const float4*)(p1 + col);
            float4 v2 = has2 ? *(const float4*)(p2 + col) : make_float4(0, 0, 0, 0);
            r0[b*4+0]=v0.x; r0[b*4+1]=v0.y; r0[b*4+2]=v0.z; r0[b*4+3]=v0.w;
            r1[b*4+0]=v1.x; r1[b*4+1]=v1.y; r1[b*4+2]=v1.z; r1[b*4+3]=v1.w;
            r2[b*4+0]=v2.x; r2[b*4+1]=v2.y; r2[b*4+2]=v2.z; r2[b*4+3]=v2.w;
        }
    } else {
#pragma unroll
        for (int i = 0; i < 12; i++) {
            int col = w0 - 4 + i;
            bool okc = (col >= 0 && col < WW);
            r0[i] = (okc && has0) ? p0[col] : 0.f;
            r1[i] =  okc          ? p1[col] : 0.f;
            r2[i] = (okc && has2) ? p2[col] : 0.f;
        }
    }

    float pxx[10], pyy[10], pxy[10];
#pragma unroll
    for (int c = 0; c < 10; c++) {
        int ai = c + 1;
        int cg = w0 - 3 + c;
        float Ix = (r0[ai+1] - r0[ai-1]) + 2.f*(r1[ai+1] - r1[ai-1]) + (r2[ai+1] - r2[ai-1]);
        float Iy = (r2[ai-1] - r0[ai-1]) + 2.f*(r2[ai]   - r0[ai])   + (r2[ai+1] - r0[ai+1]);
        bool ok = (cg >= 0 && cg < WW);
        pxx[c] = ok ? Ix * Ix : 0.f;
        pyy[c] = ok ? Iy * Iy : 0.f;
        pxy[c] = ok ? Ix * Iy : 0.f;
    }

    float oxx[4], oyy[4], oxy[4];
#pragma unroll
    for (int k = 0; k < 4; k++) {
        float sxx = 0.f, syy = 0.f, sxy = 0.f;
#pragma unroll
        for (int j = 0; j < 7; j++) {
            sxx += g.w[j] * pxx[k + j];
            syy += g.w[j] * pyy[k + j];
            sxy += g.w[j] * pxy[k + j];
        }
        oxx[k] = sxx; oyy[k] = syy; oxy[k] = sxy;
    }

    size_t base = (size_t)(n * NCH) * PIX + (size_t)h * WW + w0;
    *(float4*)(Bh + base)           = make_float4(oxx[0], oxx[1], oxx[2], oxx[3]);
    *(float4*)(Bh + base + PIX)     = make_float4(oyy[0], oyy[1], oyy[2], oyy[3]);
    *(float4*)(Bh + base + 2*PIX)   = make_float4(oxy[0], oxy[1], oxy[2], oxy[3]);
}

// ---------------- Median helpers ----------------
__device__ __forceinline__ unsigned f2key(float f) {
    unsigned b = __float_as_uint(f);
    return (b & 0x80000000u) ? ~b : (b | 0x80000000u);
}

__device__ __forceinline__ void hist4(unsigned* myh, const float4& a) {
    unsigned b0 = f2key(a.x) >> 20, b1 = f2key(a.y) >> 20,
             b2 = f2key(a.z) >> 20, b3 = f2key(a.w) >> 20;
    if (b0 == b1 && b0 == b2 && b0 == b3) {      // spatially-correlated fast path
        atomicAdd(&myh[b0], 4u);
    } else {
        atomicAdd(&myh[b0], 1u); atomicAdd(&myh[b1], 1u);
        atomicAdd(&myh[b2], 1u); atomicAdd(&myh[b3], 1u);
    }
}

// ---------------- Pass B: vertical Gaussian + fused hist0 [r6-proven] ------
__global__ __launch_bounds__(256) void gauss_v_hist(const float* __restrict__ Bh,
                                                    float* __restrict__ S, GW g) {
    __shared__ unsigned lh[2 * 4096];            // 2 lane-parity copies, 32 KB
    for (int i = threadIdx.x; i < 2 * 4096; i += 256) lh[i] = 0;
    __syncthreads();
    unsigned* myh = lh + (threadIdx.x & 1) * 4096;

    int e = blockIdx.x * 256 + threadIdx.x;      // < 12*512*512 = 3145728
    int col4  = e & (W4 - 1);
    int rg    = (e >> 9) & 511;
    int plane = e >> 18;                         // < 12
    int rbase = rg * 4;
    const float4* bp = (const float4*)Bh + (size_t)plane * (PIX / 4) + col4;
    float4*       sp = (float4*)S        + (size_t)plane * (PIX / 4) + col4;
    const float4 zero = make_float4(0, 0, 0, 0);

    float4 t[10];
#pragma unroll
    for (int j = 0; j < 10; j++) {
        int r = rbase - 3 + j;
        t[j] = (r >= 0 && r < HH) ? bp[(size_t)r * W4] : zero;
    }
#pragma unroll
    for (int k = 0; k < 4; k++) {
        float4 acc = zero;
#pragma unroll
        for (int j = 0; j < 7; j++) {
            float w = g.w[j];
            const float4& v = t[k + j];
            acc.x += w * v.x; acc.y += w * v.y;
            acc.z += w * v.z; acc.w += w * v.w;
        }
        sp[(size_t)(rbase + k) * W4] = acc;
        hist4(myh, acc);
    }

    __syncthreads();
    for (int i = threadIdx.x; i < 4096; i += 256) {
        unsigned v = lh[i] + lh[i + 4096];
        if (v) atomicAdd(&g_hist1[i], v);
    }
}

// ---------------- Pass C: mid hist (8 bits) + wave-aggregated compaction ---
// Survivors of bucket b1 are ballot-compacted into 32 region buffers in cbuf.
// Region = blockIdx&31; a region's 64 blocks scan exactly REGCAP elements, so
// region capacity REGCAP can never overflow. One atomic per wave-with-hits,
// spread over 32 counters (r3 lesson: never one hot address; r6 lesson: never
// per-block atomics on a single address at 49k-block scale — 2048 here).
__device__ __forceinline__ void proc_mid(float f, unsigned b1, unsigned* lh,
                                         unsigned* rbuf, unsigned* rcnt) {
    unsigned key = f2key(f);
    bool hit = (key >> 20) == b1;
    unsigned long long mask = __ballot(hit);
    unsigned cnt = (unsigned)__popcll(mask);
    if (cnt) {                                   // wave-uniform
        int lane = threadIdx.x & 63;
        unsigned base = 0;
        if (lane == 0) base = atomicAdd(rcnt, cnt);
        base = __shfl(base, 0);
        if (hit) {
            unsigned off = (unsigned)__popcll(mask & ((1ull << lane) - 1ull));
            rbuf[base + off] = key;
            atomicAdd(&lh[(key >> 12) & 0xFFu], 1u);
        }
    }
}

#define MIDBLOCKS 2048
__global__ __launch_bounds__(256) void hist_mid_compact(const float* __restrict__ S,
                                                        unsigned* __restrict__ cbuf) {
    __shared__ unsigned lh[256];
    if (threadIdx.x < 256) lh[threadIdx.x] = 0;
    __syncthreads();
    unsigned b1 = g_ctrl[0];
    int region = blockIdx.x & (NREG - 1);
    unsigned* rbuf = cbuf + (size_t)region * REGCAP;
    unsigned* rcnt = &g_rcount[region];

    const float4* S4 = (const float4*)S;
    const long long HALF = TOT / 8;              // 6291456 float4
    long long stride = (long long)MIDBLOCKS * 256;
    // TOT/8 / (2048*256) = 12 iterations, 2 independent float4 loads each
    for (long long i = (long long)blockIdx.x * 256 + threadIdx.x; i < HALF; i += stride) {
        float4 a = S4[i];
        float4 b = S4[i + HALF];
        proc_mid(a.x, b1, lh, rbuf, rcnt); proc_mid(a.y, b1, lh, rbuf, rcnt);
        proc_mid(a.z, b1, lh, rbuf, rcnt); proc_mid(a.w, b1, lh, rbuf, rcnt);
        proc_mid(b.x, b1, lh, rbuf, rcnt); proc_mid(b.y, b1, lh, rbuf, rcnt);
        proc_mid(b.z, b1, lh, rbuf, rcnt); proc_mid(b.w, b1, lh, rbuf, rcnt);
    }
    __syncthreads();
    if (threadIdx.x < 256) {
        unsigned v = lh[threadIdx.x];
        if (v) atomicAdd(&g_hist2[threadIdx.x], v);
    }
}

// ---------------- Pass D: low hist (12 bits) over compacted survivors ------
__global__ __launch_bounds__(256) void hist_low(const unsigned* __restrict__ cbuf) {
    __shared__ unsigned lh[4096];
    for (int i = threadIdx.x; i < 4096; i += 256) lh[i] = 0;
    __syncthreads();
    unsigned p2 = (g_ctrl[0] << 8) | g_ctrl[1];  // top 20 bits of median key
    int region = blockIdx.x & (NREG - 1);
    int sub    = blockIdx.x >> 5;                // 0..31
    const unsigned* rbuf = cbuf + (size_t)region * REGCAP;
    unsigned n = g_rcount[region];
    for (unsigned i = sub * 256 + threadIdx.x; i < n; i += 32 * 256) {
        unsigned key = rbuf[i];
        if ((key >> 12) == p2) atomicAdd(&lh[key & 0xFFFu], 1u);
    }
    __syncthreads();
    for (int i = threadIdx.x; i < 4096; i += 256) {
        unsigned v = lh[i];
        if (v) atomicAdd(&g_hist3[i], v);
    }
}

__global__ __launch_bounds__(256) void select_k(int which) {
    __shared__ unsigned cnt[4096];
    __shared__ unsigned csum[256];
    int t = threadIdx.x;
    int nbins = (which == 1) ? 256 : 4096;
    const unsigned* hsrc = (which == 0) ? g_hist1 : (which == 1) ? g_hist2 : g_hist3;
    unsigned r = (which == 0) ? MED_RANK : (which == 1) ? g_ctrl[3] : g_ctrl[4];
    int per = nbins >> 8;
    for (int i = t; i < nbins; i += 256) cnt[i] = hsrc[i];
    __syncthreads();
    unsigned s = 0;
    for (int j = 0; j < per; j++) s += cnt[t * per + j];
    csum[t] = s;
    __syncthreads();
    if (t == 0) {
        unsigned acc = 0; int c = 0;
        for (; c < 256; c++) { if (acc + csum[c] > r) break; acc += csum[c]; }
        int b = c * per;
        for (;; b++) { if (acc + cnt[b] > r) break; acc += cnt[b]; }
        if (which == 0)      { g_ctrl[0] = (unsigned)b; g_ctrl[3] = r - acc; }
        else if (which == 1) { g_ctrl[1] = (unsigned)b; g_ctrl[4] = r - acc; }
        else {
            g_ctrl[2] = (unsigned)b;
            unsigned key = (g_ctrl[0] << 20) | (g_ctrl[1] << 12) | (unsigned)b;
            unsigned bits = (key & 0x80000000u) ? (key ^ 0x80000000u) : ~key;
            g_med = __uint_as_float(bits);
        }
    }
}

// ---------------- Pass H: threshold + separable 7x7 NMS + mask [r4-proven] -
#define OX 64
#define OY 16
__global__ __launch_bounds__(256) void nms_kernel(const float* __restrict__ S,
                                                  float* __restrict__ out) {
    __shared__ float tin[22][72];
    __shared__ float hm[22][72];
    float med = g_med;                        // uniform scalar load
    int plane = blockIdx.z;
    int bx = blockIdx.x * OX, by = blockIdx.y * OY;
    const float* Sp = S + (size_t)plane * PIX;
    int t = threadIdx.x;

    for (int i = t; i < 22 * 70; i += 256) {
        int r = i / 70, c = i % 70;
        int ghh = by + r - 3, gww = bx + c - 3;
        float v = -INFINITY;                  // OOB never wins (reduce_window -inf)
        if (ghh >= 0 && ghh < HH && gww >= 0 && gww < WW) {
            float s = Sp[(size_t)ghh * WW + gww];
            v = (s > med) ? s : 0.f;
        }
        tin[r][c] = v;
    }
    __syncthreads();
    for (int i = t; i < 22 * 64; i += 256) {
        int r = i / 64, c = i % 64;
        float m = tin[r][c];
#pragma unroll
        for (int d = 1; d < 7; d++) m = fmaxf(m, tin[r][c + d]);
        hm[r][c] = m;
    }
    __syncthreads();
    int c = t & 63, rq = t >> 6;
#pragma unroll
    for (int s = 0; s < 4; s++) {
        int ro = rq * 4 + s;
        float m = hm[ro][c];
#pragma unroll
        for (int d = 1; d < 7; d++) m = fmaxf(m, hm[ro + d][c]);
        float c0 = tin[ro + 3][c + 3];
        float o = (c0 == m) ? c0 : 0.f;
        out[(size_t)plane * PIX + (size_t)(by + ro) * WW + (bx + c)] = o;
    }
}

// ---------------- Launch ----------------
extern "C" void kernel_launch(void* const* d_in, const int* in_sizes, int n_in,
                              void* d_out, int out_size, void* d_ws, size_t ws_size,
                              hipStream_t stream) {
    const float* x = (const float*)d_in[0];
    float* O = (float*)d_out;                 // Bh scratch -> cbuf -> final output
    float* W = (float*)d_ws;                  // S buffer (TOT floats)

    GW g;
    {
        double gg[7], s = 0.0;
        for (int i = 0; i < 7; i++) { double r = i - 3.0; gg[i] = exp(-r * r / 50.0); s += gg[i]; }
        for (int i = 0; i < 7; i++) g.w[i] = (float)(gg[i] / s);
    }

    zero_state<<<16, 256, 0, stream>>>();
    // A: x -> Bh (in d_out)
    sobel_gauss_h<<<dim3(WW / 1024, HH, NIMG), 256, 0, stream>>>(x, O, g);
    // B: Bh -> S (in d_ws), hist0 fused
    gauss_v_hist<<<12288, 256, 0, stream>>>(O, W, g);
    select_k<<<1, 256, 0, stream>>>(0);
    // C: scan S, 256-bin mid hist + compact survivors into d_out (Bh dead)
    hist_mid_compact<<<MIDBLOCKS, 256, 0, stream>>>(W, (unsigned*)O);
    select_k<<<1, 256, 0, stream>>>(1);
    // D: 4096-bin low hist over compacted survivors only (~44 MB)
    hist_low<<<1024, 256, 0, stream>>>((const unsigned*)O);
    select_k<<<1, 256, 0, stream>>>(2);
    // H: threshold + NMS + mask: S -> out (overwrites cbuf)
    nms_kernel<<<dim3(WW / OX, HH / OY, PLANES), 256, 0, stream>>>(W, O);
}

// Round 10
// 882.331 us; speedup vs baseline: 4.2385x; 4.2385x over previous
//
#include <hip/hip_runtime.h>
#include <math.h>

#define HH 2048
#define WW 2048
#define NIMG 4
#define NCH 3
#define PLANES (NIMG*NCH)            // 12
#define PIX (HH*WW)                  // 4194304
#define TOT (PLANES*PIX)             // 50331648
#define W4 (WW/4)                    // 512
#define MED_RANK 25165823u           // floor(0.5*(TOT-1)), method='lower'

struct GW { float w[7]; };

// ---------------- module-global device state ----------------
// Cross-kernel visibility via kernel-boundary acquire/release (r4/r7-proven).
// Radix split: 12 (top) / 8 (mid) / 12 (low) bits of the monotonic key.
// Lesson log: never allocate compaction slots with global atomics (r3: 11M on
// 1 addr; r8: dependent wave-atomics) — count, don't place. r9 lesson: every
// LDS histogram copy must be zeroed by the 256-thread block (bound your init
// loops by the ARRAY size, not a guessed thread count).
__device__ unsigned g_hist1[4096];   // pass 1: key>>20
__device__ unsigned g_hist2[256];    // pass 2: (key>>12)&0xFF within b1
__device__ unsigned g_hist3[4096];   // pass 3: key&0xFFF within (b1,b2)
__device__ unsigned g_ctrl[8];       // [0]=b1 [1]=b2 [2]=b3 [3]=rank2 [4]=rank3
__device__ float    g_med;

__global__ void zero_state() {
    int t = blockIdx.x * 256 + threadIdx.x;
    if (t < 4096) { g_hist1[t] = 0; g_hist3[t] = 0; }
    if (t < 256)  g_hist2[t] = 0;
    if (t < 8)    g_ctrl[t] = 0;
    if (t == 0)   g_med = 0.f;
}

// ---------------- Pass A: fused Sobel + horizontal Gaussian [r6-proven] ----
__global__ __launch_bounds__(256) void sobel_gauss_h(const float* __restrict__ x,
                                                     float* __restrict__ Bh, GW g) {
    int w0 = (blockIdx.x * 256 + threadIdx.x) * 4;     // 0..2044
    int h  = blockIdx.y;
    int n  = blockIdx.z;
    const float* xp = x + (size_t)n * PIX;
    const float* p0 = xp + (size_t)(h - 1) * WW;
    const float* p1 = xp + (size_t)h * WW;
    const float* p2 = xp + (size_t)(h + 1) * WW;
    bool has0 = (h > 0), has2 = (h < HH - 1);

    float r0[12], r1[12], r2[12];
    if (w0 >= 4 && w0 <= WW - 8) {          // interior: 9 float4 loads
#pragma unroll
        for (int b = 0; b < 3; b++) {
            int col = w0 - 4 + b * 4;
            float4 v0 = has0 ? *(const float4*)(p0 + col) : make_float4(0, 0, 0, 0);
            float4 v1 = *(const float4*)(p1 + col);
            float4 v2 = has2 ? *(const float4*)(p2 + col) : make_float4(0, 0, 0, 0);
            r0[b*4+0]=v0.x; r0[b*4+1]=v0.y; r0[b*4+2]=v0.z; r0[b*4+3]=v0.w;
            r1[b*4+0]=v1.x; r1[b*4+1]=v1.y; r1[b*4+2]=v1.z; r1[b*4+3]=v1.w;
            r2[b*4+0]=v2.x; r2[b*4+1]=v2.y; r2[b*4+2]=v2.z; r2[b*4+3]=v2.w;
        }
    } else {
#pragma unroll
        for (int i = 0; i < 12; i++) {
            int col = w0 - 4 + i;
            bool okc = (col >= 0 && col < WW);
            r0[i] = (okc && has0) ? p0[col] : 0.f;
            r1[i] =  okc          ? p1[col] : 0.f;
            r2[i] = (okc && has2) ? p2[col] : 0.f;
        }
    }

    float pxx[10], pyy[10], pxy[10];
#pragma unroll
    for (int c = 0; c < 10; c++) {
        int ai = c + 1;
        int cg = w0 - 3 + c;
        float Ix = (r0[ai+1] - r0[ai-1]) + 2.f*(r1[ai+1] - r1[ai-1]) + (r2[ai+1] - r2[ai-1]);
        float Iy = (r2[ai-1] - r0[ai-1]) + 2.f*(r2[ai]   - r0[ai])   + (r2[ai+1] - r0[ai+1]);
        bool ok = (cg >= 0 && cg < WW);
        pxx[c] = ok ? Ix * Ix : 0.f;
        pyy[c] = ok ? Iy * Iy : 0.f;
        pxy[c] = ok ? Ix * Iy : 0.f;
    }

    float oxx[4], oyy[4], oxy[4];
#pragma unroll
    for (int k = 0; k < 4; k++) {
        float sxx = 0.f, syy = 0.f, sxy = 0.f;
#pragma unroll
        for (int j = 0; j < 7; j++) {
            sxx += g.w[j] * pxx[k + j];
            syy += g.w[j] * pyy[k + j];
            sxy += g.w[j] * pxy[k + j];
        }
        oxx[k] = sxx; oyy[k] = syy; oxy[k] = sxy;
    }

    size_t base = (size_t)(n * NCH) * PIX + (size_t)h * WW + w0;
    *(float4*)(Bh + base)           = make_float4(oxx[0], oxx[1], oxx[2], oxx[3]);
    *(float4*)(Bh + base + PIX)     = make_float4(oyy[0], oyy[1], oyy[2], oyy[3]);
    *(float4*)(Bh + base + 2*PIX)   = make_float4(oxy[0], oxy[1], oxy[2], oxy[3]);
}

// ---------------- Median helpers ----------------
__device__ __forceinline__ unsigned f2key(float f) {
    unsigned b = __float_as_uint(f);
    return (b & 0x80000000u) ? ~b : (b | 0x80000000u);
}

__device__ __forceinline__ void hist4(unsigned* myh, const float4& a) {
    unsigned b0 = f2key(a.x) >> 20, b1 = f2key(a.y) >> 20,
             b2 = f2key(a.z) >> 20, b3 = f2key(a.w) >> 20;
    if (b0 == b1 && b0 == b2 && b0 == b3) {      // spatially-correlated fast path
        atomicAdd(&myh[b0], 4u);
    } else {
        atomicAdd(&myh[b0], 1u); atomicAdd(&myh[b1], 1u);
        atomicAdd(&myh[b2], 1u); atomicAdd(&myh[b3], 1u);
    }
}

// ---------------- Pass B: vertical Gaussian + fused hist0 [r6/r7-proven] ---
__global__ __launch_bounds__(256) void gauss_v_hist(const float* __restrict__ Bh,
                                                    float* __restrict__ S, GW g) {
    __shared__ unsigned lh[2 * 4096];            // 2 lane-parity copies, 32 KB
    for (int i = threadIdx.x; i < 2 * 4096; i += 256) lh[i] = 0;
    __syncthreads();
    unsigned* myh = lh + (threadIdx.x & 1) * 4096;

    int e = blockIdx.x * 256 + threadIdx.x;      // < 12*512*512 = 3145728
    int col4  = e & (W4 - 1);
    int rg    = (e >> 9) & 511;
    int plane = e >> 18;                         // < 12
    int rbase = rg * 4;
    const float4* bp = (const float4*)Bh + (size_t)plane * (PIX / 4) + col4;
    float4*       sp = (float4*)S        + (size_t)plane * (PIX / 4) + col4;
    const float4 zero = make_float4(0, 0, 0, 0);

    float4 t[10];
#pragma unroll
    for (int j = 0; j < 10; j++) {
        int r = rbase - 3 + j;
        t[j] = (r >= 0 && r < HH) ? bp[(size_t)r * W4] : zero;
    }
#pragma unroll
    for (int k = 0; k < 4; k++) {
        float4 acc = zero;
#pragma unroll
        for (int j = 0; j < 7; j++) {
            float w = g.w[j];
            const float4& v = t[k + j];
            acc.x += w * v.x; acc.y += w * v.y;
            acc.z += w * v.z; acc.w += w * v.w;
        }
        sp[(size_t)(rbase + k) * W4] = acc;
        hist4(myh, acc);
    }

    __syncthreads();
    for (int i = threadIdx.x; i < 4096; i += 256) {
        unsigned v = lh[i] + lh[i + 4096];
        if (v) atomicAdd(&g_hist1[i], v);
    }
}

// ---------------- Pass C: mid hist — 256 bins, 2 KB LDS, deep ILP ----------
__global__ __launch_bounds__(256) void hist_mid(const float* __restrict__ S) {
    __shared__ unsigned lh[2 * 256];
    lh[threadIdx.x] = 0;                         // copy 0
    lh[threadIdx.x + 256] = 0;                   // copy 1 (r9 bug: was missed)
    __syncthreads();
    unsigned* myh = lh + (threadIdx.x & 1) * 256;
    unsigned b1 = g_ctrl[0];
    const float4* S4 = (const float4*)S;
    const long long HALF = TOT / 8;              // 6291456 float4
    long long stride = (long long)gridDim.x * 256;
    for (long long i = (long long)blockIdx.x * 256 + threadIdx.x; i < HALF; i += stride) {
        float4 a = S4[i];
        float4 b = S4[i + HALF];                 // 2 independent streams for MLP
        unsigned k0 = f2key(a.x), k1 = f2key(a.y), k2 = f2key(a.z), k3 = f2key(a.w);
        unsigned k4 = f2key(b.x), k5 = f2key(b.y), k6 = f2key(b.z), k7 = f2key(b.w);
        if ((k0 >> 20) == b1) atomicAdd(&myh[(k0 >> 12) & 0xFFu], 1u);
        if ((k1 >> 20) == b1) atomicAdd(&myh[(k1 >> 12) & 0xFFu], 1u);
        if ((k2 >> 20) == b1) atomicAdd(&myh[(k2 >> 12) & 0xFFu], 1u);
        if ((k3 >> 20) == b1) atomicAdd(&myh[(k3 >> 12) & 0xFFu], 1u);
        if ((k4 >> 20) == b1) atomicAdd(&myh[(k4 >> 12) & 0xFFu], 1u);
        if ((k5 >> 20) == b1) atomicAdd(&myh[(k5 >> 12) & 0xFFu], 1u);
        if ((k6 >> 20) == b1) atomicAdd(&myh[(k6 >> 12) & 0xFFu], 1u);
        if ((k7 >> 20) == b1) atomicAdd(&myh[(k7 >> 12) & 0xFFu], 1u);
    }
    __syncthreads();
    if (threadIdx.x < 256) {
        unsigned v = lh[threadIdx.x] + lh[threadIdx.x + 256];
        if (v) atomicAdd(&g_hist2[threadIdx.x], v);
    }
}

// ---------------- Pass D: low hist — 4096 bins, top-20-bit filter ----------
// Survivors of the 20-bit prefix are rare (~50K of 50M) -> atomics negligible;
// this is a pure streaming scan.
__global__ __launch_bounds__(256) void hist_low(const float* __restrict__ S) {
    __shared__ unsigned lh[4096];                // 16 KB
    for (int i = threadIdx.x; i < 4096; i += 256) lh[i] = 0;
    __syncthreads();
    unsigned p2 = (g_ctrl[0] << 8) | g_ctrl[1];  // top 20 bits of median key
    const float4* S4 = (const float4*)S;
    const long long HALF = TOT / 8;
    long long stride = (long long)gridDim.x * 256;
    for (long long i = (long long)blockIdx.x * 256 + threadIdx.x; i < HALF; i += stride) {
        float4 a = S4[i];
        float4 b = S4[i + HALF];
        unsigned k0 = f2key(a.x), k1 = f2key(a.y), k2 = f2key(a.z), k3 = f2key(a.w);
        unsigned k4 = f2key(b.x), k5 = f2key(b.y), k6 = f2key(b.z), k7 = f2key(b.w);
        if ((k0 >> 12) == p2) atomicAdd(&lh[k0 & 0xFFFu], 1u);
        if ((k1 >> 12) == p2) atomicAdd(&lh[k1 & 0xFFFu], 1u);
        if ((k2 >> 12) == p2) atomicAdd(&lh[k2 & 0xFFFu], 1u);
        if ((k3 >> 12) == p2) atomicAdd(&lh[k3 & 0xFFFu], 1u);
        if ((k4 >> 12) == p2) atomicAdd(&lh[k4 & 0xFFFu], 1u);
        if ((k5 >> 12) == p2) atomicAdd(&lh[k5 & 0xFFFu], 1u);
        if ((k6 >> 12) == p2) atomicAdd(&lh[k6 & 0xFFFu], 1u);
        if ((k7 >> 12) == p2) atomicAdd(&lh[k7 & 0xFFFu], 1u);
    }
    __syncthreads();
    for (int i = threadIdx.x; i < 4096; i += 256) {
        unsigned v = lh[i];
        if (v) atomicAdd(&g_hist3[i], v);
    }
}

__global__ __launch_bounds__(256) void select_k(int which) {
    __shared__ unsigned cnt[4096];
    __shared__ unsigned csum[256];
    int t = threadIdx.x;
    int nbins = (which == 1) ? 256 : 4096;
    const unsigned* hsrc = (which == 0) ? g_hist1 : (which == 1) ? g_hist2 : g_hist3;
    unsigned r = (which == 0) ? MED_RANK : (which == 1) ? g_ctrl[3] : g_ctrl[4];
    int per = nbins >> 8;
    for (int i = t; i < nbins; i += 256) cnt[i] = hsrc[i];
    __syncthreads();
    unsigned s = 0;
    for (int j = 0; j < per; j++) s += cnt[t * per + j];
    csum[t] = s;
    __syncthreads();
    if (t == 0) {
        unsigned acc = 0; int c = 0;
        for (; c < 256; c++) { if (acc + csum[c] > r) break; acc += csum[c]; }
        int b = c * per;
        for (;; b++) { if (acc + cnt[b] > r) break; acc += cnt[b]; }
        if (which == 0)      { g_ctrl[0] = (unsigned)b; g_ctrl[3] = r - acc; }
        else if (which == 1) { g_ctrl[1] = (unsigned)b; g_ctrl[4] = r - acc; }
        else {
            g_ctrl[2] = (unsigned)b;
            unsigned key = (g_ctrl[0] << 20) | (g_ctrl[1] << 12) | (unsigned)b;
            unsigned bits = (key & 0x80000000u) ? (key ^ 0x80000000u) : ~key;
            g_med = __uint_as_float(bits);
        }
    }
}

// ---------------- Pass H: threshold + separable 7x7 NMS + mask [r4-proven] -
#define OX 64
#define OY 16
__global__ __launch_bounds__(256) void nms_kernel(const float* __restrict__ S,
                                                  float* __restrict__ out) {
    __shared__ float tin[22][72];
    __shared__ float hm[22][72];
    float med = g_med;                        // uniform scalar load
    int plane = blockIdx.z;
    int bx = blockIdx.x * OX, by = blockIdx.y * OY;
    const float* Sp = S + (size_t)plane * PIX;
    int t = threadIdx.x;

    for (int i = t; i < 22 * 70; i += 256) {
        int r = i / 70, c = i % 70;
        int ghh = by + r - 3, gww = bx + c - 3;
        float v = -INFINITY;                  // OOB never wins (reduce_window -inf)
        if (ghh >= 0 && ghh < HH && gww >= 0 && gww < WW) {
            float s = Sp[(size_t)ghh * WW + gww];
            v = (s > med) ? s : 0.f;
        }
        tin[r][c] = v;
    }
    __syncthreads();
    for (int i = t; i < 22 * 64; i += 256) {
        int r = i / 64, c = i % 64;
        float m = tin[r][c];
#pragma unroll
        for (int d = 1; d < 7; d++) m = fmaxf(m, tin[r][c + d]);
        hm[r][c] = m;
    }
    __syncthreads();
    int c = t & 63, rq = t >> 6;
#pragma unroll
    for (int s = 0; s < 4; s++) {
        int ro = rq * 4 + s;
        float m = hm[ro][c];
#pragma unroll
        for (int d = 1; d < 7; d++) m = fmaxf(m, hm[ro + d][c]);
        float c0 = tin[ro + 3][c + 3];
        float o = (c0 == m) ? c0 : 0.f;
        out[(size_t)plane * PIX + (size_t)(by + ro) * WW + (bx + c)] = o;
    }
}

// ---------------- Launch ----------------
extern "C" void kernel_launch(void* const* d_in, const int* in_sizes, int n_in,
                              void* d_out, int out_size, void* d_ws, size_t ws_size,
                              hipStream_t stream) {
    const float* x = (const float*)d_in[0];
    float* O = (float*)d_out;                 // Bh scratch -> final output
    float* W = (float*)d_ws;                  // S buffer (TOT floats)

    GW g;
    {
        double gg[7], s = 0.0;
        for (int i = 0; i < 7; i++) { double r = i - 3.0; gg[i] = exp(-r * r / 50.0); s += gg[i]; }
        for (int i = 0; i < 7; i++) g.w[i] = (float)(gg[i] / s);
    }

    zero_state<<<16, 256, 0, stream>>>();
    // A: x -> Bh (in d_out)
    sobel_gauss_h<<<dim3(WW / 1024, HH, NIMG), 256, 0, stream>>>(x, O, g);
    // B: Bh -> S (in d_ws), hist0 fused
    gauss_v_hist<<<12288, 256, 0, stream>>>(O, W, g);
    select_k<<<1, 256, 0, stream>>>(0);
    // C: 256-bin mid hist (12/8/12 split), full-occupancy streaming scan
    hist_mid<<<8192, 256, 0, stream>>>(W);
    select_k<<<1, 256, 0, stream>>>(1);
    // D: 4096-bin low hist, top-20-bit filter (rare hits)
    hist_low<<<8192, 256, 0, stream>>>(W);
    select_k<<<1, 256, 0, stream>>>(2);
    // H: threshold + NMS + mask: S -> out
    nms_kernel<<<dim3(WW / OX, HH / OY, PLANES), 256, 0, stream>>>(W, O);
}

// Round 11
// 729.836 us; speedup vs baseline: 5.1241x; 1.2089x over previous
//
#include <hip/hip_runtime.h>
#include <math.h>

#define HH 2048
#define WW 2048
#define NIMG 4
#define NCH 3
#define PLANES (NIMG*NCH)            // 12
#define PIX (HH*WW)                  // 4194304
#define TOT (PLANES*PIX)             // 50331648
#define W4 (WW/4)                    // 512
#define MED_RANK 25165823u           // floor(0.5*(TOT-1)), method='lower'

struct GW { float w[7]; };

// ---------------- module-global device state ----------------
// Cross-kernel visibility via kernel-boundary acquire/release (r4/r7-proven).
// Radix split: 12 (top) / 8 (mid) / 12 (low) bits of the monotonic key.
// Lesson log: (r3/r8) never allocate compaction slots with global atomics —
// count, don't place. (r9) zero ALL LDS histogram copies. (r10) scans are
// MLP-limited: ~2 outstanding loads/wave caps at ~900 GB/s; need >=8.
__device__ unsigned g_hist1[4096];   // pass 1: key>>20
__device__ unsigned g_hist2[256];    // pass 2: (key>>12)&0xFF within b1
__device__ unsigned g_hist3[4096];   // pass 3: key&0xFFF within (b1,b2)
__device__ unsigned g_ctrl[8];       // [0]=b1 [1]=b2 [2]=b3 [3]=rank2 [4]=rank3
__device__ float    g_med;

__global__ void zero_state() {
    int t = blockIdx.x * 256 + threadIdx.x;
    if (t < 4096) { g_hist1[t] = 0; g_hist3[t] = 0; }
    if (t < 256)  g_hist2[t] = 0;
    if (t < 8)    g_ctrl[t] = 0;
    if (t == 0)   g_med = 0.f;
}

// ---------------- Pass A: fused Sobel + horizontal Gaussian [r6-proven] ----
__global__ __launch_bounds__(256) void sobel_gauss_h(const float* __restrict__ x,
                                                     float* __restrict__ Bh, GW g) {
    int w0 = (blockIdx.x * 256 + threadIdx.x) * 4;     // 0..2044
    int h  = blockIdx.y;
    int n  = blockIdx.z;
    const float* xp = x + (size_t)n * PIX;
    const float* p0 = xp + (size_t)(h - 1) * WW;
    const float* p1 = xp + (size_t)h * WW;
    const float* p2 = xp + (size_t)(h + 1) * WW;
    bool has0 = (h > 0), has2 = (h < HH - 1);

    float r0[12], r1[12], r2[12];
    if (w0 >= 4 && w0 <= WW - 8) {          // interior: 9 float4 loads
#pragma unroll
        for (int b = 0; b < 3; b++) {
            int col = w0 - 4 + b * 4;
            float4 v0 = has0 ? *(const float4*)(p0 + col) : make_float4(0, 0, 0, 0);
            float4 v1 = *(const float4*)(p1 + col);
            float4 v2 = has2 ? *(const float4*)(p2 + col) : make_float4(0, 0, 0, 0);
            r0[b*4+0]=v0.x; r0[b*4+1]=v0.y; r0[b*4+2]=v0.z; r0[b*4+3]=v0.w;
            r1[b*4+0]=v1.x; r1[b*4+1]=v1.y; r1[b*4+2]=v1.z; r1[b*4+3]=v1.w;
            r2[b*4+0]=v2.x; r2[b*4+1]=v2.y; r2[b*4+2]=v2.z; r2[b*4+3]=v2.w;
        }
    } else {
#pragma unroll
        for (int i = 0; i < 12; i++) {
            int col = w0 - 4 + i;
            bool okc = (col >= 0 && col < WW);
            r0[i] = (okc && has0) ? p0[col] : 0.f;
            r1[i] =  okc          ? p1[col] : 0.f;
            r2[i] = (okc && has2) ? p2[col] : 0.f;
        }
    }

    float pxx[10], pyy[10], pxy[10];
#pragma unroll
    for (int c = 0; c < 10; c++) {
        int ai = c + 1;
        int cg = w0 - 3 + c;
        float Ix = (r0[ai+1] - r0[ai-1]) + 2.f*(r1[ai+1] - r1[ai-1]) + (r2[ai+1] - r2[ai-1]);
        float Iy = (r2[ai-1] - r0[ai-1]) + 2.f*(r2[ai]   - r0[ai])   + (r2[ai+1] - r0[ai+1]);
        bool ok = (cg >= 0 && cg < WW);
        pxx[c] = ok ? Ix * Ix : 0.f;
        pyy[c] = ok ? Iy * Iy : 0.f;
        pxy[c] = ok ? Ix * Iy : 0.f;
    }

    float oxx[4], oyy[4], oxy[4];
#pragma unroll
    for (int k = 0; k < 4; k++) {
        float sxx = 0.f, syy = 0.f, sxy = 0.f;
#pragma unroll
        for (int j = 0; j < 7; j++) {
            sxx += g.w[j] * pxx[k + j];
            syy += g.w[j] * pyy[k + j];
            sxy += g.w[j] * pxy[k + j];
        }
        oxx[k] = sxx; oyy[k] = syy; oxy[k] = sxy;
    }

    size_t base = (size_t)(n * NCH) * PIX + (size_t)h * WW + w0;
    *(float4*)(Bh + base)           = make_float4(oxx[0], oxx[1], oxx[2], oxx[3]);
    *(float4*)(Bh + base + PIX)     = make_float4(oyy[0], oyy[1], oyy[2], oyy[3]);
    *(float4*)(Bh + base + 2*PIX)   = make_float4(oxy[0], oxy[1], oxy[2], oxy[3]);
}

// ---------------- Median helpers ----------------
__device__ __forceinline__ unsigned f2key(float f) {
    unsigned b = __float_as_uint(f);
    return (b & 0x80000000u) ? ~b : (b | 0x80000000u);
}

__device__ __forceinline__ void hist4(unsigned* myh, const float4& a) {
    unsigned b0 = f2key(a.x) >> 20, b1 = f2key(a.y) >> 20,
             b2 = f2key(a.z) >> 20, b3 = f2key(a.w) >> 20;
    if (b0 == b1 && b0 == b2 && b0 == b3) {      // spatially-correlated fast path
        atomicAdd(&myh[b0], 4u);
    } else {
        atomicAdd(&myh[b0], 1u); atomicAdd(&myh[b1], 1u);
        atomicAdd(&myh[b2], 1u); atomicAdd(&myh[b3], 1u);
    }
}

// ---------------- Pass B: vertical Gaussian + fused hist0 [r6/r7-proven] ---
__global__ __launch_bounds__(256) void gauss_v_hist(const float* __restrict__ Bh,
                                                    float* __restrict__ S, GW g) {
    __shared__ unsigned lh[2 * 4096];            // 2 lane-parity copies, 32 KB
    for (int i = threadIdx.x; i < 2 * 4096; i += 256) lh[i] = 0;
    __syncthreads();
    unsigned* myh = lh + (threadIdx.x & 1) * 4096;

    int e = blockIdx.x * 256 + threadIdx.x;      // < 12*512*512 = 3145728
    int col4  = e & (W4 - 1);
    int rg    = (e >> 9) & 511;
    int plane = e >> 18;                         // < 12
    int rbase = rg * 4;
    const float4* bp = (const float4*)Bh + (size_t)plane * (PIX / 4) + col4;
    float4*       sp = (float4*)S        + (size_t)plane * (PIX / 4) + col4;
    const float4 zero = make_float4(0, 0, 0, 0);

    float4 t[10];
#pragma unroll
    for (int j = 0; j < 10; j++) {
        int r = rbase - 3 + j;
        t[j] = (r >= 0 && r < HH) ? bp[(size_t)r * W4] : zero;
    }
#pragma unroll
    for (int k = 0; k < 4; k++) {
        float4 acc = zero;
#pragma unroll
        for (int j = 0; j < 7; j++) {
            float w = g.w[j];
            const float4& v = t[k + j];
            acc.x += w * v.x; acc.y += w * v.y;
            acc.z += w * v.z; acc.w += w * v.w;
        }
        sp[(size_t)(rbase + k) * W4] = acc;
        hist4(myh, acc);
    }

    __syncthreads();
    for (int i = threadIdx.x; i < 4096; i += 256) {
        unsigned v = lh[i] + lh[i + 4096];
        if (v) atomicAdd(&g_hist1[i], v);
    }
}

// ---------------- Pass C: mid hist — 8-stream MLP scan, 256 bins -----------
#define SCAN_BLOCKS 2048
#define NSTR 8
#define SLAB (TOT / 4 / NSTR)        // 1572864 float4 per slab
__global__ __launch_bounds__(256) void hist_mid(const float* __restrict__ S) {
    __shared__ unsigned lh[2 * 256];
    lh[threadIdx.x] = 0;
    lh[threadIdx.x + 256] = 0;
    __syncthreads();
    unsigned* myh = lh + (threadIdx.x & 1) * 256;
    unsigned b1 = g_ctrl[0];
    const float4* S4 = (const float4*)S;
    long long stride = (long long)SCAN_BLOCKS * 256;
    // SLAB / stride = 3 iterations; 8 independent loads in flight per iter.
    for (long long i = (long long)blockIdx.x * 256 + threadIdx.x; i < SLAB; i += stride) {
        float4 v[NSTR];
#pragma unroll
        for (int s = 0; s < NSTR; s++) v[s] = S4[i + (long long)s * SLAB];
#pragma unroll
        for (int s = 0; s < NSTR; s++) {
            unsigned k0 = f2key(v[s].x), k1 = f2key(v[s].y),
                     k2 = f2key(v[s].z), k3 = f2key(v[s].w);
            if ((k0 >> 20) == b1) atomicAdd(&myh[(k0 >> 12) & 0xFFu], 1u);
            if ((k1 >> 20) == b1) atomicAdd(&myh[(k1 >> 12) & 0xFFu], 1u);
            if ((k2 >> 20) == b1) atomicAdd(&myh[(k2 >> 12) & 0xFFu], 1u);
            if ((k3 >> 20) == b1) atomicAdd(&myh[(k3 >> 12) & 0xFFu], 1u);
        }
    }
    __syncthreads();
    if (threadIdx.x < 256) {
        unsigned v = lh[threadIdx.x] + lh[threadIdx.x + 256];
        if (v) atomicAdd(&g_hist2[threadIdx.x], v);
    }
}

// ---------------- Pass D: low hist — 8-stream MLP scan, 4096 bins ----------
__global__ __launch_bounds__(256) void hist_low(const float* __restrict__ S) {
    __shared__ unsigned lh[4096];                // 16 KB
    for (int i = threadIdx.x; i < 4096; i += 256) lh[i] = 0;
    __syncthreads();
    unsigned p2 = (g_ctrl[0] << 8) | g_ctrl[1];  // top 20 bits of median key
    const float4* S4 = (const float4*)S;
    long long stride = (long long)SCAN_BLOCKS * 256;
    for (long long i = (long long)blockIdx.x * 256 + threadIdx.x; i < SLAB; i += stride) {
        float4 v[NSTR];
#pragma unroll
        for (int s = 0; s < NSTR; s++) v[s] = S4[i + (long long)s * SLAB];
#pragma unroll
        for (int s = 0; s < NSTR; s++) {
            unsigned k0 = f2key(v[s].x), k1 = f2key(v[s].y),
                     k2 = f2key(v[s].z), k3 = f2key(v[s].w);
            if ((k0 >> 12) == p2) atomicAdd(&lh[k0 & 0xFFFu], 1u);
            if ((k1 >> 12) == p2) atomicAdd(&lh[k1 & 0xFFFu], 1u);
            if ((k2 >> 12) == p2) atomicAdd(&lh[k2 & 0xFFFu], 1u);
            if ((k3 >> 12) == p2) atomicAdd(&lh[k3 & 0xFFFu], 1u);
        }
    }
    __syncthreads();
    for (int i = threadIdx.x; i < 4096; i += 256) {
        unsigned v = lh[i];
        if (v) atomicAdd(&g_hist3[i], v);
    }
}

__global__ __launch_bounds__(256) void select_k(int which) {
    __shared__ unsigned cnt[4096];
    __shared__ unsigned csum[256];
    int t = threadIdx.x;
    int nbins = (which == 1) ? 256 : 4096;
    const unsigned* hsrc = (which == 0) ? g_hist1 : (which == 1) ? g_hist2 : g_hist3;
    unsigned r = (which == 0) ? MED_RANK : (which == 1) ? g_ctrl[3] : g_ctrl[4];
    int per = nbins >> 8;
    for (int i = t; i < nbins; i += 256) cnt[i] = hsrc[i];
    __syncthreads();
    unsigned s = 0;
    for (int j = 0; j < per; j++) s += cnt[t * per + j];
    csum[t] = s;
    __syncthreads();
    if (t == 0) {
        unsigned acc = 0; int c = 0;
        for (; c < 256; c++) { if (acc + csum[c] > r) break; acc += csum[c]; }
        int b = c * per;
        for (;; b++) { if (acc + cnt[b] > r) break; acc += cnt[b]; }
        if (which == 0)      { g_ctrl[0] = (unsigned)b; g_ctrl[3] = r - acc; }
        else if (which == 1) { g_ctrl[1] = (unsigned)b; g_ctrl[4] = r - acc; }
        else {
            g_ctrl[2] = (unsigned)b;
            unsigned key = (g_ctrl[0] << 20) | (g_ctrl[1] << 12) | (unsigned)b;
            unsigned bits = (key & 0x80000000u) ? (key ^ 0x80000000u) : ~key;
            g_med = __uint_as_float(bits);
        }
    }
}

// ---------------- Pass H: threshold + separable 7x7 NMS + mask [r4-proven] -
#define OX 64
#define OY 16
__global__ __launch_bounds__(256) void nms_kernel(const float* __restrict__ S,
                                                  float* __restrict__ out) {
    __shared__ float tin[22][72];
    __shared__ float hm[22][72];
    float med = g_med;                        // uniform scalar load
    int plane = blockIdx.z;
    int bx = blockIdx.x * OX, by = blockIdx.y * OY;
    const float* Sp = S + (size_t)plane * PIX;
    int t = threadIdx.x;

    for (int i = t; i < 22 * 70; i += 256) {
        int r = i / 70, c = i % 70;
        int ghh = by + r - 3, gww = bx + c - 3;
        float v = -INFINITY;                  // OOB never wins (reduce_window -inf)
        if (ghh >= 0 && ghh < HH && gww >= 0 && gww < WW) {
            float s = Sp[(size_t)ghh * WW + gww];
            v = (s > med) ? s : 0.f;
        }
        tin[r][c] = v;
    }
    __syncthreads();
    for (int i = t; i < 22 * 64; i += 256) {
        int r = i / 64, c = i % 64;
        float m = tin[r][c];
#pragma unroll
        for (int d = 1; d < 7; d++) m = fmaxf(m, tin[r][c + d]);
        hm[r][c] = m;
    }
    __syncthreads();
    int c = t & 63, rq = t >> 6;
#pragma unroll
    for (int s = 0; s < 4; s++) {
        int ro = rq * 4 + s;
        float m = hm[ro][c];
#pragma unroll
        for (int d = 1; d < 7; d++) m = fmaxf(m, hm[ro + d][c]);
        float c0 = tin[ro + 3][c + 3];
        float o = (c0 == m) ? c0 : 0.f;
        out[(size_t)plane * PIX + (size_t)(by + ro) * WW + (bx + c)] = o;
    }
}

// ---------------- Launch ----------------
extern "C" void kernel_launch(void* const* d_in, const int* in_sizes, int n_in,
                              void* d_out, int out_size, void* d_ws, size_t ws_size,
                              hipStream_t stream) {
    const float* x = (const float*)d_in[0];
    float* O = (float*)d_out;                 // Bh scratch -> final output
    float* W = (float*)d_ws;                  // S buffer (TOT floats)

    GW g;
    {
        double gg[7], s = 0.0;
        for (int i = 0; i < 7; i++) { double r = i - 3.0; gg[i] = exp(-r * r / 50.0); s += gg[i]; }
        for (int i = 0; i < 7; i++) g.w[i] = (float)(gg[i] / s);
    }

    zero_state<<<16, 256, 0, stream>>>();
    // A: x -> Bh (in d_out)
    sobel_gauss_h<<<dim3(WW / 1024, HH, NIMG), 256, 0, stream>>>(x, O, g);
    // B: Bh -> S (in d_ws), hist0 fused
    gauss_v_hist<<<12288, 256, 0, stream>>>(O, W, g);
    select_k<<<1, 256, 0, stream>>>(0);
    // C: 256-bin mid hist, 8-stream MLP scan
    hist_mid<<<SCAN_BLOCKS, 256, 0, stream>>>(W);
    select_k<<<1, 256, 0, stream>>>(1);
    // D: 4096-bin low hist, 8-stream MLP scan
    hist_low<<<SCAN_BLOCKS, 256, 0, stream>>>(W);
    select_k<<<1, 256, 0, stream>>>(2);
    // H: threshold + NMS + mask: S -> out
    nms_kernel<<<dim3(WW / OX, HH / OY, PLANES), 256, 0, stream>>>(W, O);
}

// Round 12
// 673.571 us; speedup vs baseline: 5.5521x; 1.0835x over previous
//
#include <hip/hip_runtime.h>
#include <math.h>

#define HH 2048
#define WW 2048
#define NIMG 4
#define NCH 3
#define PLANES (NIMG*NCH)            // 12
#define PIX (HH*WW)                  // 4194304
#define TOT (PLANES*PIX)             // 50331648
#define W4 (WW/4)                    // 512
#define MED_RANK 25165823u           // floor(0.5*(TOT-1)), method='lower'

struct GW { float w[7]; };

// ---------------- module-global device state ----------------
// Cross-kernel visibility via kernel-boundary acquire/release (r4/r7-proven).
// Radix split: 8 (top) / 12 (mid) / 12 (low) bits of the monotonic key.
// Lessons: (r3/r8) count, don't place (no atomic slot allocation). (r9) zero
// every LDS copy. (r10) scans need >=8 loads in flight. (r6) no per-block
// atomics on one hot address — partial copies + reduce instead.
#define H1C 64                       // partial copies for pass-1 hist
#define H23C 16                      // partial copies for pass-2/3 hists
__device__ unsigned g_hist1p[H1C * 256];
__device__ unsigned g_hist2p[H23C * 4096];
__device__ unsigned g_hist3p[H23C * 4096];
__device__ unsigned g_ctrl[8];       // [0]=b1 [1]=b2 [2]=b3 [3]=rank2 [4]=rank3
__device__ float    g_med;

__global__ void zero_state() {       // launched with 256 blocks x 256
    int t = blockIdx.x * 256 + threadIdx.x;   // < 65536
    if (t < H1C * 256) g_hist1p[t] = 0;
    g_hist2p[t] = 0;
    g_hist3p[t] = 0;
    if (t < 8) g_ctrl[t] = 0;
    if (t == 0) g_med = 0.f;
}

// ---------------- Pass A: fused Sobel + horizontal Gaussian [r6-proven] ----
__global__ __launch_bounds__(256) void sobel_gauss_h(const float* __restrict__ x,
                                                     float* __restrict__ Bh, GW g) {
    int w0 = (blockIdx.x * 256 + threadIdx.x) * 4;     // 0..2044
    int h  = blockIdx.y;
    int n  = blockIdx.z;
    const float* xp = x + (size_t)n * PIX;
    const float* p0 = xp + (size_t)(h - 1) * WW;
    const float* p1 = xp + (size_t)h * WW;
    const float* p2 = xp + (size_t)(h + 1) * WW;
    bool has0 = (h > 0), has2 = (h < HH - 1);

    float r0[12], r1[12], r2[12];
    if (w0 >= 4 && w0 <= WW - 8) {          // interior: 9 float4 loads
#pragma unroll
        for (int b = 0; b < 3; b++) {
            int col = w0 - 4 + b * 4;
            float4 v0 = has0 ? *(const float4*)(p0 + col) : make_float4(0, 0, 0, 0);
            float4 v1 = *(const float4*)(p1 + col);
            float4 v2 = has2 ? *(const float4*)(p2 + col) : make_float4(0, 0, 0, 0);
            r0[b*4+0]=v0.x; r0[b*4+1]=v0.y; r0[b*4+2]=v0.z; r0[b*4+3]=v0.w;
            r1[b*4+0]=v1.x; r1[b*4+1]=v1.y; r1[b*4+2]=v1.z; r1[b*4+3]=v1.w;
            r2[b*4+0]=v2.x; r2[b*4+1]=v2.y; r2[b*4+2]=v2.z; r2[b*4+3]=v2.w;
        }
    } else {
#pragma unroll
        for (int i = 0; i < 12; i++) {
            int col = w0 - 4 + i;
            bool okc = (col >= 0 && col < WW);
            r0[i] = (okc && has0) ? p0[col] : 0.f;
            r1[i] =  okc          ? p1[col] : 0.f;
            r2[i] = (okc && has2) ? p2[col] : 0.f;
        }
    }

    float pxx[10], pyy[10], pxy[10];
#pragma unroll
    for (int c = 0; c < 10; c++) {
        int ai = c + 1;
        int cg = w0 - 3 + c;
        float Ix = (r0[ai+1] - r0[ai-1]) + 2.f*(r1[ai+1] - r1[ai-1]) + (r2[ai+1] - r2[ai-1]);
        float Iy = (r2[ai-1] - r0[ai-1]) + 2.f*(r2[ai]   - r0[ai])   + (r2[ai+1] - r0[ai+1]);
        bool ok = (cg >= 0 && cg < WW);
        pxx[c] = ok ? Ix * Ix : 0.f;
        pyy[c] = ok ? Iy * Iy : 0.f;
        pxy[c] = ok ? Ix * Iy : 0.f;
    }

    float oxx[4], oyy[4], oxy[4];
#pragma unroll
    for (int k = 0; k < 4; k++) {
        float sxx = 0.f, syy = 0.f, sxy = 0.f;
#pragma unroll
        for (int j = 0; j < 7; j++) {
            sxx += g.w[j] * pxx[k + j];
            syy += g.w[j] * pyy[k + j];
            sxy += g.w[j] * pxy[k + j];
        }
        oxx[k] = sxx; oyy[k] = syy; oxy[k] = sxy;
    }

    size_t base = (size_t)(n * NCH) * PIX + (size_t)h * WW + w0;
    *(float4*)(Bh + base)           = make_float4(oxx[0], oxx[1], oxx[2], oxx[3]);
    *(float4*)(Bh + base + PIX)     = make_float4(oyy[0], oyy[1], oyy[2], oyy[3]);
    *(float4*)(Bh + base + 2*PIX)   = make_float4(oxy[0], oxy[1], oxy[2], oxy[3]);
}

// ---------------- Median helpers ----------------
__device__ __forceinline__ unsigned f2key(float f) {
    unsigned b = __float_as_uint(f);
    return (b & 0x80000000u) ? ~b : (b | 0x80000000u);
}

// Wave-collective histogram add: all 64 lanes participate (exact full-wave
// launches only). All-lanes-same-bucket (spatially correlated, common) -> one
// atomicAdd(+64) by lane 0; else per-lane atomic.
__device__ __forceinline__ void hist_add_wave(unsigned* lh, unsigned bucket) {
    unsigned first = __builtin_amdgcn_readfirstlane(bucket);
    unsigned long long m = __ballot(bucket == first);
    if (m == 0xFFFFFFFFFFFFFFFFull) {
        if ((threadIdx.x & 63) == 0) atomicAdd(&lh[first], 64u);
    } else {
        atomicAdd(&lh[bucket], 1u);
    }
}

// ---------------- Pass B: vertical Gaussian + fused 8-bit hist0 ------------
// Thread = one float4 column x 4 rows (r6-proven mapping). 256-bin LDS hist
// (1 KB), wave-aggregated adds, flush to 64 partial copies.
__global__ __launch_bounds__(256) void gauss_v_hist(const float* __restrict__ Bh,
                                                    float* __restrict__ S, GW g) {
    __shared__ unsigned lh[256];
    lh[threadIdx.x] = 0;
    __syncthreads();

    int e = blockIdx.x * 256 + threadIdx.x;      // < 12*512*512 = 3145728
    int col4  = e & (W4 - 1);
    int rg    = (e >> 9) & 511;
    int plane = e >> 18;                         // < 12
    int rbase = rg * 4;
    const float4* bp = (const float4*)Bh + (size_t)plane * (PIX / 4) + col4;
    float4*       sp = (float4*)S        + (size_t)plane * (PIX / 4) + col4;
    const float4 zero = make_float4(0, 0, 0, 0);

    float4 t[10];
#pragma unroll
    for (int j = 0; j < 10; j++) {
        int r = rbase - 3 + j;
        t[j] = (r >= 0 && r < HH) ? bp[(size_t)r * W4] : zero;
    }
#pragma unroll
    for (int k = 0; k < 4; k++) {
        float4 acc = zero;
#pragma unroll
        for (int j = 0; j < 7; j++) {
            float w = g.w[j];
            const float4& v = t[k + j];
            acc.x += w * v.x; acc.y += w * v.y;
            acc.z += w * v.z; acc.w += w * v.w;
        }
        sp[(size_t)(rbase + k) * W4] = acc;
        hist_add_wave(lh, f2key(acc.x) >> 24);
        hist_add_wave(lh, f2key(acc.y) >> 24);
        hist_add_wave(lh, f2key(acc.z) >> 24);
        hist_add_wave(lh, f2key(acc.w) >> 24);
    }

    __syncthreads();
    unsigned v = lh[threadIdx.x];
    if (v) atomicAdd(&g_hist1p[(blockIdx.x & (H1C - 1)) * 256 + threadIdx.x], v);
}

// ---------------- Pass C: mid hist — 8-stream scan, 4096 bins --------------
#define SCAN_BLOCKS 2048
#define NSTR 8
#define SLAB (TOT / 4 / NSTR)        // 1572864 float4 per slab
__global__ __launch_bounds__(256) void hist_mid(const float* __restrict__ S) {
    __shared__ unsigned lh[4096];                // 16 KB
    for (int i = threadIdx.x; i < 4096; i += 256) lh[i] = 0;
    __syncthreads();
    unsigned b1 = g_ctrl[0];
    const float4* S4 = (const float4*)S;
    long long stride = (long long)SCAN_BLOCKS * 256;
    for (long long i = (long long)blockIdx.x * 256 + threadIdx.x; i < SLAB; i += stride) {
        float4 v[NSTR];
#pragma unroll
        for (int s = 0; s < NSTR; s++) v[s] = S4[i + (long long)s * SLAB];
#pragma unroll
        for (int s = 0; s < NSTR; s++) {
            unsigned k0 = f2key(v[s].x), k1 = f2key(v[s].y),
                     k2 = f2key(v[s].z), k3 = f2key(v[s].w);
            if ((k0 >> 24) == b1) atomicAdd(&lh[(k0 >> 12) & 0xFFFu], 1u);
            if ((k1 >> 24) == b1) atomicAdd(&lh[(k1 >> 12) & 0xFFFu], 1u);
            if ((k2 >> 24) == b1) atomicAdd(&lh[(k2 >> 12) & 0xFFFu], 1u);
            if ((k3 >> 24) == b1) atomicAdd(&lh[(k3 >> 12) & 0xFFFu], 1u);
        }
    }
    __syncthreads();
    unsigned cpy = (blockIdx.x & (H23C - 1)) * 4096;
    for (int i = threadIdx.x; i < 4096; i += 256) {
        unsigned v = lh[i];
        if (v) atomicAdd(&g_hist2p[cpy + i], v);
    }
}

// ---------------- Pass D: low hist — 8-stream scan, 4096 bins --------------
__global__ __launch_bounds__(256) void hist_low(const float* __restrict__ S) {
    __shared__ unsigned lh[4096];                // 16 KB
    for (int i = threadIdx.x; i < 4096; i += 256) lh[i] = 0;
    __syncthreads();
    unsigned p2 = (g_ctrl[0] << 12) | g_ctrl[1]; // top 20 bits of median key
    const float4* S4 = (const float4*)S;
    long long stride = (long long)SCAN_BLOCKS * 256;
    for (long long i = (long long)blockIdx.x * 256 + threadIdx.x; i < SLAB; i += stride) {
        float4 v[NSTR];
#pragma unroll
        for (int s = 0; s < NSTR; s++) v[s] = S4[i + (long long)s * SLAB];
#pragma unroll
        for (int s = 0; s < NSTR; s++) {
            unsigned k0 = f2key(v[s].x), k1 = f2key(v[s].y),
                     k2 = f2key(v[s].z), k3 = f2key(v[s].w);
            if ((k0 >> 12) == p2) atomicAdd(&lh[k0 & 0xFFFu], 1u);
            if ((k1 >> 12) == p2) atomicAdd(&lh[k1 & 0xFFFu], 1u);
            if ((k2 >> 12) == p2) atomicAdd(&lh[k2 & 0xFFFu], 1u);
            if ((k3 >> 12) == p2) atomicAdd(&lh[k3 & 0xFFFu], 1u);
        }
    }
    __syncthreads();
    unsigned cpy = (blockIdx.x & (H23C - 1)) * 4096;
    for (int i = threadIdx.x; i < 4096; i += 256) {
        unsigned v = lh[i];
        if (v) atomicAdd(&g_hist3p[cpy + i], v);
    }
}

// ---------------- bucket select over partial-copy histograms ---------------
__global__ __launch_bounds__(256) void select_k(int which) {
    __shared__ unsigned cnt[4096];
    __shared__ unsigned csum[256];
    int t = threadIdx.x;
    int nbins = (which == 0) ? 256 : 4096;
    // reduce partial copies into cnt[]
    if (which == 0) {
        unsigned s = 0;
        for (int c = 0; c < H1C; c++) s += g_hist1p[c * 256 + t];
        cnt[t] = s;
    } else {
        const unsigned* hp = (which == 1) ? g_hist2p : g_hist3p;
        for (int i = t; i < 4096; i += 256) {
            unsigned s = 0;
            for (int c = 0; c < H23C; c++) s += hp[c * 4096 + i];
            cnt[i] = s;
        }
    }
    __syncthreads();
    int per = nbins >> 8;
    unsigned s = 0;
    for (int j = 0; j < per; j++) s += cnt[t * per + j];
    csum[t] = s;
    __syncthreads();
    if (t == 0) {
        unsigned r = (which == 0) ? MED_RANK : (which == 1) ? g_ctrl[3] : g_ctrl[4];
        unsigned acc = 0; int c = 0;
        for (; c < 256; c++) { if (acc + csum[c] > r) break; acc += csum[c]; }
        int b = c * per;
        for (;; b++) { if (acc + cnt[b] > r) break; acc += cnt[b]; }
        if (which == 0)      { g_ctrl[0] = (unsigned)b; g_ctrl[3] = r - acc; }
        else if (which == 1) { g_ctrl[1] = (unsigned)b; g_ctrl[4] = r - acc; }
        else {
            g_ctrl[2] = (unsigned)b;
            unsigned key = (g_ctrl[0] << 24) | (g_ctrl[1] << 12) | (unsigned)b;
            unsigned bits = (key & 0x80000000u) ? (key ^ 0x80000000u) : ~key;
            g_med = __uint_as_float(bits);
        }
    }
}

// ---------------- Pass H: threshold + separable 7x7 NMS + mask [r4-proven] -
#define OX 64
#define OY 16
__global__ __launch_bounds__(256) void nms_kernel(const float* __restrict__ S,
                                                  float* __restrict__ out) {
    __shared__ float tin[22][72];
    __shared__ float hm[22][72];
    float med = g_med;                        // uniform scalar load
    int plane = blockIdx.z;
    int bx = blockIdx.x * OX, by = blockIdx.y * OY;
    const float* Sp = S + (size_t)plane * PIX;
    int t = threadIdx.x;

    for (int i = t; i < 22 * 70; i += 256) {
        int r = i / 70, c = i % 70;
        int ghh = by + r - 3, gww = bx + c - 3;
        float v = -INFINITY;                  // OOB never wins (reduce_window -inf)
        if (ghh >= 0 && ghh < HH && gww >= 0 && gww < WW) {
            float s = Sp[(size_t)ghh * WW + gww];
            v = (s > med) ? s : 0.f;
        }
        tin[r][c] = v;
    }
    __syncthreads();
    for (int i = t; i < 22 * 64; i += 256) {
        int r = i / 64, c = i % 64;
        float m = tin[r][c];
#pragma unroll
        for (int d = 1; d < 7; d++) m = fmaxf(m, tin[r][c + d]);
        hm[r][c] = m;
    }
    __syncthreads();
    int c = t & 63, rq = t >> 6;
#pragma unroll
    for (int s = 0; s < 4; s++) {
        int ro = rq * 4 + s;
        float m = hm[ro][c];
#pragma unroll
        for (int d = 1; d < 7; d++) m = fmaxf(m, hm[ro + d][c]);
        float c0 = tin[ro + 3][c + 3];
        float o = (c0 == m) ? c0 : 0.f;
        out[(size_t)plane * PIX + (size_t)(by + ro) * WW + (bx + c)] = o;
    }
}

// ---------------- Launch ----------------
extern "C" void kernel_launch(void* const* d_in, const int* in_sizes, int n_in,
                              void* d_out, int out_size, void* d_ws, size_t ws_size,
                              hipStream_t stream) {
    const float* x = (const float*)d_in[0];
    float* O = (float*)d_out;                 // Bh scratch -> final output
    float* W = (float*)d_ws;                  // S buffer (TOT floats)

    GW g;
    {
        double gg[7], s = 0.0;
        for (int i = 0; i < 7; i++) { double r = i - 3.0; gg[i] = exp(-r * r / 50.0); s += gg[i]; }
        for (int i = 0; i < 7; i++) g.w[i] = (float)(gg[i] / s);
    }

    zero_state<<<256, 256, 0, stream>>>();
    // A: x -> Bh (in d_out)
    sobel_gauss_h<<<dim3(WW / 1024, HH, NIMG), 256, 0, stream>>>(x, O, g);
    // B: Bh -> S (in d_ws), 8-bit hist0 fused (wave-aggregated, 1 KB LDS)
    gauss_v_hist<<<12288, 256, 0, stream>>>(O, W, g);
    select_k<<<1, 256, 0, stream>>>(0);
    // C: 4096-bin mid hist (8/12/12 split), 8-stream MLP scan
    hist_mid<<<SCAN_BLOCKS, 256, 0, stream>>>(W);
    select_k<<<1, 256, 0, stream>>>(1);
    // D: 4096-bin low hist, top-20-bit filter
    hist_low<<<SCAN_BLOCKS, 256, 0, stream>>>(W);
    select_k<<<1, 256, 0, stream>>>(2);
    // H: threshold + NMS + mask: S -> out
    nms_kernel<<<dim3(WW / OX, HH / OY, PLANES), 256, 0, stream>>>(W, O);
}

// Round 13
// 597.020 us; speedup vs baseline: 6.2640x; 1.1282x over previous
//
#include <hip/hip_runtime.h>
#include <math.h>

#define HH 2048
#define WW 2048
#define NIMG 4
#define NCH 3
#define PLANES (NIMG*NCH)            // 12
#define PIX (HH*WW)                  // 4194304
#define TOT (PLANES*PIX)             // 50331648
#define W4 (WW/4)                    // 512
#define MED_RANK 25165823u           // floor(0.5*(TOT-1)), method='lower'

struct GW { float w[7]; };

// ---------------- module-global device state ----------------
// Cross-kernel visibility via kernel-boundary acquire/release (r4/r7-proven).
// Radix split: 8 (top) / 12 (mid) / 12 (low). Lessons: (r3/r8) count, don't
// place; (r9) zero every LDS copy; (r10) >=8 loads in flight; (r6) no hot
// global addresses; (r12) LDS same-address atomics serialize per-lane — use
// replicated copies at stride 257 (co-prime with 32 banks).
#define H1C 64                       // partial copies for pass-1 hist
#define H23C 16                      // partial copies for pass-2/3 hists
__device__ unsigned g_hist1p[H1C * 256];
__device__ unsigned g_hist2p[H23C * 4096];
__device__ unsigned g_hist3p[H23C * 4096];
__device__ unsigned g_ctrl[8];       // [0]=b1 [1]=b2 [2]=b3 [3]=rank2 [4]=rank3
__device__ float    g_med;

__global__ void zero_state() {       // launched with 256 blocks x 256
    int t = blockIdx.x * 256 + threadIdx.x;   // < 65536
    if (t < H1C * 256) g_hist1p[t] = 0;
    g_hist2p[t] = 0;
    g_hist3p[t] = 0;
    if (t < 8) g_ctrl[t] = 0;
    if (t == 0) g_med = 0.f;
}

// ---------------- Pass A: fused Sobel + horizontal Gaussian [r6-proven] ----
__global__ __launch_bounds__(256) void sobel_gauss_h(const float* __restrict__ x,
                                                     float* __restrict__ Bh, GW g) {
    int w0 = (blockIdx.x * 256 + threadIdx.x) * 4;     // 0..2044
    int h  = blockIdx.y;
    int n  = blockIdx.z;
    const float* xp = x + (size_t)n * PIX;
    const float* p0 = xp + (size_t)(h - 1) * WW;
    const float* p1 = xp + (size_t)h * WW;
    const float* p2 = xp + (size_t)(h + 1) * WW;
    bool has0 = (h > 0), has2 = (h < HH - 1);

    float r0[12], r1[12], r2[12];
    if (w0 >= 4 && w0 <= WW - 8) {          // interior: 9 float4 loads
#pragma unroll
        for (int b = 0; b < 3; b++) {
            int col = w0 - 4 + b * 4;
            float4 v0 = has0 ? *(const float4*)(p0 + col) : make_float4(0, 0, 0, 0);
            float4 v1 = *(const float4*)(p1 + col);
            float4 v2 = has2 ? *(const float4*)(p2 + col) : make_float4(0, 0, 0, 0);
            r0[b*4+0]=v0.x; r0[b*4+1]=v0.y; r0[b*4+2]=v0.z; r0[b*4+3]=v0.w;
            r1[b*4+0]=v1.x; r1[b*4+1]=v1.y; r1[b*4+2]=v1.z; r1[b*4+3]=v1.w;
            r2[b*4+0]=v2.x; r2[b*4+1]=v2.y; r2[b*4+2]=v2.z; r2[b*4+3]=v2.w;
        }
    } else {
#pragma unroll
        for (int i = 0; i < 12; i++) {
            int col = w0 - 4 + i;
            bool okc = (col >= 0 && col < WW);
            r0[i] = (okc && has0) ? p0[col] : 0.f;
            r1[i] =  okc          ? p1[col] : 0.f;
            r2[i] = (okc && has2) ? p2[col] : 0.f;
        }
    }

    float pxx[10], pyy[10], pxy[10];
#pragma unroll
    for (int c = 0; c < 10; c++) {
        int ai = c + 1;
        int cg = w0 - 3 + c;
        float Ix = (r0[ai+1] - r0[ai-1]) + 2.f*(r1[ai+1] - r1[ai-1]) + (r2[ai+1] - r2[ai-1]);
        float Iy = (r2[ai-1] - r0[ai-1]) + 2.f*(r2[ai]   - r0[ai])   + (r2[ai+1] - r0[ai+1]);
        bool ok = (cg >= 0 && cg < WW);
        pxx[c] = ok ? Ix * Ix : 0.f;
        pyy[c] = ok ? Iy * Iy : 0.f;
        pxy[c] = ok ? Ix * Iy : 0.f;
    }

    float oxx[4], oyy[4], oxy[4];
#pragma unroll
    for (int k = 0; k < 4; k++) {
        float sxx = 0.f, syy = 0.f, sxy = 0.f;
#pragma unroll
        for (int j = 0; j < 7; j++) {
            sxx += g.w[j] * pxx[k + j];
            syy += g.w[j] * pyy[k + j];
            sxy += g.w[j] * pxy[k + j];
        }
        oxx[k] = sxx; oyy[k] = syy; oxy[k] = sxy;
    }

    size_t base = (size_t)(n * NCH) * PIX + (size_t)h * WW + w0;
    *(float4*)(Bh + base)           = make_float4(oxx[0], oxx[1], oxx[2], oxx[3]);
    *(float4*)(Bh + base + PIX)     = make_float4(oyy[0], oyy[1], oyy[2], oyy[3]);
    *(float4*)(Bh + base + 2*PIX)   = make_float4(oxy[0], oxy[1], oxy[2], oxy[3]);
}

// ---------------- Median helpers ----------------
__device__ __forceinline__ unsigned f2key(float f) {
    unsigned b = __float_as_uint(f);
    return (b & 0x80000000u) ? ~b : (b | 0x80000000u);
}

// ---------------- Pass B: vertical Gaussian + fused 8-bit hist0 ------------
// 8 replicated LDS hist copies at stride 257 (co-prime w/ 32 banks): fallback
// same-bucket collisions drop 64-way -> 8-way. Fully-uniform wave -> 1 atomic.
#define HCOPY 8
#define HSTRIDE 257
__global__ __launch_bounds__(256) void gauss_v_hist(const float* __restrict__ Bh,
                                                    float* __restrict__ S, GW g) {
    __shared__ unsigned lh[HCOPY * HSTRIDE];     // 8.2 KB
    for (int i = threadIdx.x; i < HCOPY * HSTRIDE; i += 256) lh[i] = 0;
    __syncthreads();
    unsigned* myh = lh + (threadIdx.x & (HCOPY - 1)) * HSTRIDE;

    int e = blockIdx.x * 256 + threadIdx.x;      // < 12*512*512 = 3145728
    int col4  = e & (W4 - 1);
    int rg    = (e >> 9) & 511;
    int plane = e >> 18;                         // < 12
    int rbase = rg * 4;
    const float4* bp = (const float4*)Bh + (size_t)plane * (PIX / 4) + col4;
    float4*       sp = (float4*)S        + (size_t)plane * (PIX / 4) + col4;
    const float4 zero = make_float4(0, 0, 0, 0);

    float4 t[10];
#pragma unroll
    for (int j = 0; j < 10; j++) {
        int r = rbase - 3 + j;
        t[j] = (r >= 0 && r < HH) ? bp[(size_t)r * W4] : zero;
    }
#pragma unroll
    for (int k = 0; k < 4; k++) {
        float4 acc = zero;
#pragma unroll
        for (int j = 0; j < 7; j++) {
            float w = g.w[j];
            const float4& v = t[k + j];
            acc.x += w * v.x; acc.y += w * v.y;
            acc.z += w * v.z; acc.w += w * v.w;
        }
        sp[(size_t)(rbase + k) * W4] = acc;
        unsigned bk[4] = { f2key(acc.x) >> 24, f2key(acc.y) >> 24,
                           f2key(acc.z) >> 24, f2key(acc.w) >> 24 };
#pragma unroll
        for (int q = 0; q < 4; q++) {
            unsigned first = __builtin_amdgcn_readfirstlane(bk[q]);
            unsigned long long m = __ballot(bk[q] == first);
            if (m == 0xFFFFFFFFFFFFFFFFull) {
                if ((threadIdx.x & 63) == 0) atomicAdd(&lh[first], 64u);
            } else {
                atomicAdd(&myh[bk[q]], 1u);
            }
        }
    }

    __syncthreads();
    if (threadIdx.x < 256) {
        unsigned v = 0;
#pragma unroll
        for (int c = 0; c < HCOPY; c++) v += lh[c * HSTRIDE + threadIdx.x];
        if (v) atomicAdd(&g_hist1p[(blockIdx.x & (H1C - 1)) * 256 + threadIdx.x], v);
    }
}

// ---------------- Pass C: mid hist — 8-stream scan, 4096 bins --------------
#define SCAN_BLOCKS 2048
#define NSTR 8
#define SLAB (TOT / 4 / NSTR)        // 1572864 float4 per slab
__global__ __launch_bounds__(256) void hist_mid(const float* __restrict__ S) {
    __shared__ unsigned lh[4096];                // 16 KB
    for (int i = threadIdx.x; i < 4096; i += 256) lh[i] = 0;
    __syncthreads();
    unsigned b1 = g_ctrl[0];
    const float4* S4 = (const float4*)S;
    long long stride = (long long)SCAN_BLOCKS * 256;
    for (long long i = (long long)blockIdx.x * 256 + threadIdx.x; i < SLAB; i += stride) {
        float4 v[NSTR];
#pragma unroll
        for (int s = 0; s < NSTR; s++) v[s] = S4[i + (long long)s * SLAB];
#pragma unroll
        for (int s = 0; s < NSTR; s++) {
            unsigned k0 = f2key(v[s].x), k1 = f2key(v[s].y),
                     k2 = f2key(v[s].z), k3 = f2key(v[s].w);
            if ((k0 >> 24) == b1) atomicAdd(&lh[(k0 >> 12) & 0xFFFu], 1u);
            if ((k1 >> 24) == b1) atomicAdd(&lh[(k1 >> 12) & 0xFFFu], 1u);
            if ((k2 >> 24) == b1) atomicAdd(&lh[(k2 >> 12) & 0xFFFu], 1u);
            if ((k3 >> 24) == b1) atomicAdd(&lh[(k3 >> 12) & 0xFFFu], 1u);
        }
    }
    __syncthreads();
    unsigned cpy = (blockIdx.x & (H23C - 1)) * 4096;
    for (int i = threadIdx.x; i < 4096; i += 256) {
        unsigned v = lh[i];
        if (v) atomicAdd(&g_hist2p[cpy + i], v);
    }
}

// ---------------- Pass D: low hist — 8-stream scan, 4096 bins --------------
__global__ __launch_bounds__(256) void hist_low(const float* __restrict__ S) {
    __shared__ unsigned lh[4096];                // 16 KB
    for (int i = threadIdx.x; i < 4096; i += 256) lh[i] = 0;
    __syncthreads();
    unsigned p2 = (g_ctrl[0] << 12) | g_ctrl[1]; // top 20 bits of median key
    const float4* S4 = (const float4*)S;
    long long stride = (long long)SCAN_BLOCKS * 256;
    for (long long i = (long long)blockIdx.x * 256 + threadIdx.x; i < SLAB; i += stride) {
        float4 v[NSTR];
#pragma unroll
        for (int s = 0; s < NSTR; s++) v[s] = S4[i + (long long)s * SLAB];
#pragma unroll
        for (int s = 0; s < NSTR; s++) {
            unsigned k0 = f2key(v[s].x), k1 = f2key(v[s].y),
                     k2 = f2key(v[s].z), k3 = f2key(v[s].w);
            if ((k0 >> 12) == p2) atomicAdd(&lh[k0 & 0xFFFu], 1u);
            if ((k1 >> 12) == p2) atomicAdd(&lh[k1 & 0xFFFu], 1u);
            if ((k2 >> 12) == p2) atomicAdd(&lh[k2 & 0xFFFu], 1u);
            if ((k3 >> 12) == p2) atomicAdd(&lh[k3 & 0xFFFu], 1u);
        }
    }
    __syncthreads();
    unsigned cpy = (blockIdx.x & (H23C - 1)) * 4096;
    for (int i = threadIdx.x; i < 4096; i += 256) {
        unsigned v = lh[i];
        if (v) atomicAdd(&g_hist3p[cpy + i], v);
    }
}

// ---------------- bucket select over partial-copy histograms ---------------
__global__ __launch_bounds__(256) void select_k(int which) {
    __shared__ unsigned cnt[4096];
    __shared__ unsigned csum[256];
    int t = threadIdx.x;
    int nbins = (which == 0) ? 256 : 4096;
    if (which == 0) {
        unsigned s = 0;
        for (int c = 0; c < H1C; c++) s += g_hist1p[c * 256 + t];
        cnt[t] = s;
    } else {
        const unsigned* hp = (which == 1) ? g_hist2p : g_hist3p;
        for (int i = t; i < 4096; i += 256) {
            unsigned s = 0;
            for (int c = 0; c < H23C; c++) s += hp[c * 4096 + i];
            cnt[i] = s;
        }
    }
    __syncthreads();
    int per = nbins >> 8;
    unsigned s = 0;
    for (int j = 0; j < per; j++) s += cnt[t * per + j];
    csum[t] = s;
    __syncthreads();
    if (t == 0) {
        unsigned r = (which == 0) ? MED_RANK : (which == 1) ? g_ctrl[3] : g_ctrl[4];
        unsigned acc = 0; int c = 0;
        for (; c < 256; c++) { if (acc + csum[c] > r) break; acc += csum[c]; }
        int b = c * per;
        for (;; b++) { if (acc + cnt[b] > r) break; acc += cnt[b]; }
        if (which == 0)      { g_ctrl[0] = (unsigned)b; g_ctrl[3] = r - acc; }
        else if (which == 1) { g_ctrl[1] = (unsigned)b; g_ctrl[4] = r - acc; }
        else {
            g_ctrl[2] = (unsigned)b;
            unsigned key = (g_ctrl[0] << 24) | (g_ctrl[1] << 12) | (unsigned)b;
            unsigned bits = (key & 0x80000000u) ? (key ^ 0x80000000u) : ~key;
            g_med = __uint_as_float(bits);
        }
    }
}

// ---------------- Pass H: threshold + 7x7 NMS + mask — all-float4 ----------
// Tile 64x16. Halo cols [bx-4,bx+68) are float4-aligned and either fully
// in-image or fully OOB (bx % 64 == 0) -> no per-element guards anywhere.
#define OX 64
#define OY 16
__global__ __launch_bounds__(256) void nms_kernel(const float* __restrict__ S,
                                                  float* __restrict__ out) {
    __shared__ float tin[22][72];     // rows by-3..by+18, cols bx-4..bx+67
    __shared__ float hm[22][68];      // h-max, cols bx..bx+63 (stride 68: b128-aligned rows)
    float med = g_med;
    int plane = blockIdx.z;
    int bx = blockIdx.x * OX, by = blockIdx.y * OY;
    const float* Sp = S + (size_t)plane * PIX;
    int t = threadIdx.x;

    // stage: 22 rows x 18 float4, thresholded; OOB float4 -> -inf
    for (int i = t; i < 22 * 18; i += 256) {
        int r = i / 18, cc = i % 18;
        int ghh = by + r - 3;
        int gc  = bx - 4 + cc * 4;
        float4 v = make_float4(-INFINITY, -INFINITY, -INFINITY, -INFINITY);
        if (ghh >= 0 && ghh < HH && gc >= 0 && gc < WW) {
            float4 s = *(const float4*)(Sp + (size_t)ghh * WW + gc);
            v.x = (s.x > med) ? s.x : 0.f;
            v.y = (s.y > med) ? s.y : 0.f;
            v.z = (s.z > med) ? s.z : 0.f;
            v.w = (s.w > med) ? s.w : 0.f;
        }
        *(float4*)&tin[r][cc * 4] = v;
    }
    __syncthreads();

    // h-max: task = (row r, col-group c): hm[r][4c+j] = max tin[r][4c+j+1..4c+j+7]
    for (int i = t; i < 22 * 16; i += 256) {
        int r = i / 16, c = i % 16;
        float a0 = tin[r][4*c+1], a1 = tin[r][4*c+2], a2 = tin[r][4*c+3];
        float a3 = tin[r][4*c+4], a4 = tin[r][4*c+5], a5 = tin[r][4*c+6];
        float a6 = tin[r][4*c+7], a7 = tin[r][4*c+8], a8 = tin[r][4*c+9];
        float a9 = tin[r][4*c+10];
        float m03 = fmaxf(fmaxf(a0, a1), fmaxf(a2, a3));
        float m36 = fmaxf(fmaxf(a3, a4), fmaxf(a5, a6));
        float4 o;
        o.x = fmaxf(m03, fmaxf(fmaxf(a4, a5), a6));
        o.y = fmaxf(fmaxf(a1, a2), fmaxf(m36, a7));
        o.z = fmaxf(fmaxf(a2, a3), fmaxf(fmaxf(a4, m36), fmaxf(a7, a8)));
        o.w = fmaxf(m36, fmaxf(fmaxf(a7, a8), a9));
        *(float4*)&hm[r][4*c] = o;
    }
    __syncthreads();

    // v-max + center compare + write: thread = (row ro = t>>4, col-group cc = t&15)
    int cc = t & 15, ro = t >> 4;
    float4 m = *(const float4*)&hm[ro][4*cc];
#pragma unroll
    for (int d = 1; d < 7; d++) {
        float4 h = *(const float4*)&hm[ro + d][4*cc];
        m.x = fmaxf(m.x, h.x); m.y = fmaxf(m.y, h.y);
        m.z = fmaxf(m.z, h.z); m.w = fmaxf(m.w, h.w);
    }
    float4 c0 = *(const float4*)&tin[ro + 3][4*cc + 4];
    float4 o;
    o.x = (c0.x == m.x) ? c0.x : 0.f;
    o.y = (c0.y == m.y) ? c0.y : 0.f;
    o.z = (c0.z == m.z) ? c0.z : 0.f;
    o.w = (c0.w == m.w) ? c0.w : 0.f;
    *(float4*)(out + (size_t)plane * PIX + (size_t)(by + ro) * WW + bx + 4*cc) = o;
}

// ---------------- Launch ----------------
extern "C" void kernel_launch(void* const* d_in, const int* in_sizes, int n_in,
                              void* d_out, int out_size, void* d_ws, size_t ws_size,
                              hipStream_t stream) {
    const float* x = (const float*)d_in[0];
    float* O = (float*)d_out;                 // Bh scratch -> final output
    float* W = (float*)d_ws;                  // S buffer (TOT floats)

    GW g;
    {
        double gg[7], s = 0.0;
        for (int i = 0; i < 7; i++) { double r = i - 3.0; gg[i] = exp(-r * r / 50.0); s += gg[i]; }
        for (int i = 0; i < 7; i++) g.w[i] = (float)(gg[i] / s);
    }

    zero_state<<<256, 256, 0, stream>>>();
    // A: x -> Bh (in d_out)
    sobel_gauss_h<<<dim3(WW / 1024, HH, NIMG), 256, 0, stream>>>(x, O, g);
    // B: Bh -> S (in d_ws), 8-bit hist0 fused (8-copy LDS hist)
    gauss_v_hist<<<12288, 256, 0, stream>>>(O, W, g);
    select_k<<<1, 256, 0, stream>>>(0);
    // C: 4096-bin mid hist (8/12/12 split), 8-stream MLP scan
    hist_mid<<<SCAN_BLOCKS, 256, 0, stream>>>(W);
    select_k<<<1, 256, 0, stream>>>(1);
    // D: 4096-bin low hist, top-20-bit filter
    hist_low<<<SCAN_BLOCKS, 256, 0, stream>>>(W);
    select_k<<<1, 256, 0, stream>>>(2);
    // H: threshold + NMS + mask: S -> out (all-float4)
    nms_kernel<<<dim3(WW / OX, HH / OY, PLANES), 256, 0, stream>>>(W, O);
}

// Round 14
// 517.422 us; speedup vs baseline: 7.2277x; 1.1538x over previous
//
#include <hip/hip_runtime.h>
#include <math.h>

#define HH 2048
#define WW 2048
#define NIMG 4
#define NCH 3
#define PLANES (NIMG*NCH)            // 12
#define PIX (HH*WW)                  // 4194304
#define TOT (PLANES*PIX)             // 50331648
#define W4 (WW/4)                    // 512
#define MED_RANK 25165823u           // floor(0.5*(TOT-1)), method='lower'

struct GW { float w[7]; };

// ---------------- module-global device state ----------------
// Cross-kernel visibility via kernel-boundary acquire/release (r4/r7-proven).
// Radix split: 8 (top) / 12 (mid) / 12 (low). Lessons: (r3/r8) count, don't
// place; (r9) zero every LDS copy; (r10) >=8 loads in flight; (r6) no hot
// global addresses; (r12) LDS same-address atomics serialize — replicate.
#define H1C 64
#define H23C 16
__device__ unsigned g_hist1p[H1C * 256];
__device__ unsigned g_hist2p[H23C * 4096];
__device__ unsigned g_hist3p[H23C * 4096];
__device__ unsigned g_ctrl[8];       // [0]=b1 [1]=b2 [2]=b3 [3]=rank2 [4]=rank3
__device__ float    g_med;

__global__ void zero_state() {       // 256 blocks x 256
    int t = blockIdx.x * 256 + threadIdx.x;   // < 65536
    if (t < H1C * 256) g_hist1p[t] = 0;
    g_hist2p[t] = 0;
    g_hist3p[t] = 0;
    if (t < 8) g_ctrl[t] = 0;
    if (t == 0) g_med = 0.f;
}

// ---------------- Median helpers ----------------
__device__ __forceinline__ unsigned f2key(float f) {
    unsigned b = __float_as_uint(f);
    return (b & 0x80000000u) ? ~b : (b | 0x80000000u);
}

#define HCOPY 8
#define HSTRIDE 257

__device__ __forceinline__ void hist_add(unsigned* lh, unsigned* myh, unsigned bucket) {
    unsigned first = __builtin_amdgcn_readfirstlane(bucket);
    unsigned long long m = __ballot(bucket == first);
    if (m == 0xFFFFFFFFFFFFFFFFull) {
        if ((threadIdx.x & 63) == 0) atomicAdd(&lh[first], 64u);
    } else {
        atomicAdd(&myh[bucket], 1u);
    }
}

// ---------------- Megakernel: Sobel + full 7x7 Gaussian + hist0 ------------
// Tile: 64 rows x 32 cols x 3 channels per block. x tile and Bh tile live in
// LDS; S is written once; Bh never touches HBM. Components: pass-A 4-col
// register scheme [r6-proven], pass-B 7-tap [r6-proven], 8-copy ballot hist
// [r13-proven]. Reference semantics: products (not sobel-of-pad) are
// zero-padded for the Gaussian -> Bh rows/cols mapping to OOB image are 0.
#define TX 32
#define TY 64
__global__ __launch_bounds__(256) void sobel_gauss_full(const float* __restrict__ x,
                                                        float* __restrict__ S, GW g) {
    __shared__ float xs[72][40];        // image rows by-4..by+67, cols bx-4..bx+35
    __shared__ float bh[3][70][36];     // Bh rows by-3..by+66, cols bx..bx+31
    __shared__ unsigned lh[HCOPY * HSTRIDE];
    for (int i = threadIdx.x; i < HCOPY * HSTRIDE; i += 256) lh[i] = 0;
    unsigned* myh = lh + (threadIdx.x & (HCOPY - 1)) * HSTRIDE;

    int bx = blockIdx.x * TX, by = blockIdx.y * TY;
    int n = blockIdx.z;
    const float* xp = x + (size_t)n * PIX;
    int t = threadIdx.x;

    // ---- stage x tile: 72 rows x 10 float4, zero-fill OOB ----
    for (int i = t; i < 72 * 10; i += 256) {
        int r = i / 10, cc = i % 10;
        int gr = by - 4 + r, gc = bx - 4 + cc * 4;
        float4 v = make_float4(0, 0, 0, 0);
        if (gr >= 0 && gr < HH && gc >= 0 && gc < WW)
            v = *(const float4*)(xp + (size_t)gr * WW + gc);
        *(float4*)&xs[r][cc * 4] = v;
    }
    __syncthreads();

    // ---- stage Bh: 70 rows x 8 col-groups (4 cols each), 3 channels ----
    for (int i = t; i < 70 * 8; i += 256) {
        int r = i >> 3, c = i & 7;
        int imgrow = by - 3 + r;
        if (imgrow < 0 || imgrow >= HH) {     // products zero-padded vertically
            float4 z = make_float4(0, 0, 0, 0);
            *(float4*)&bh[0][r][4 * c] = z;
            *(float4*)&bh[1][r][4 * c] = z;
            *(float4*)&bh[2][r][4 * c] = z;
            continue;
        }
        float r0[12], r1[12], r2[12];
#pragma unroll
        for (int b = 0; b < 3; b++) {
            float4 v0 = *(float4*)&xs[r][4 * c + 4 * b];
            float4 v1 = *(float4*)&xs[r + 1][4 * c + 4 * b];
            float4 v2 = *(float4*)&xs[r + 2][4 * c + 4 * b];
            r0[b*4+0]=v0.x; r0[b*4+1]=v0.y; r0[b*4+2]=v0.z; r0[b*4+3]=v0.w;
            r1[b*4+0]=v1.x; r1[b*4+1]=v1.y; r1[b*4+2]=v1.z; r1[b*4+3]=v1.w;
            r2[b*4+0]=v2.x; r2[b*4+1]=v2.y; r2[b*4+2]=v2.z; r2[b*4+3]=v2.w;
        }
        float pxx[10], pyy[10], pxy[10];
#pragma unroll
        for (int p = 0; p < 10; p++) {
            int ai = p + 1;
            int cg = bx + 4 * c - 3 + p;      // image col of this product
            float Ix = (r0[ai+1] - r0[ai-1]) + 2.f*(r1[ai+1] - r1[ai-1]) + (r2[ai+1] - r2[ai-1]);
            float Iy = (r2[ai-1] - r0[ai-1]) + 2.f*(r2[ai]   - r0[ai])   + (r2[ai+1] - r0[ai+1]);
            bool ok = (cg >= 0 && cg < WW);   // products zero-padded horizontally
            pxx[p] = ok ? Ix * Ix : 0.f;
            pyy[p] = ok ? Iy * Iy : 0.f;
            pxy[p] = ok ? Ix * Iy : 0.f;
        }
        float4 oxx, oyy, oxy;
        float* ox = &oxx.x; float* oy = &oyy.x; float* oz = &oxy.x;
#pragma unroll
        for (int k = 0; k < 4; k++) {
            float sxx = 0.f, syy = 0.f, sxy = 0.f;
#pragma unroll
            for (int j = 0; j < 7; j++) {
                sxx += g.w[j] * pxx[k + j];
                syy += g.w[j] * pyy[k + j];
                sxy += g.w[j] * pxy[k + j];
            }
            ox[k] = sxx; oy[k] = syy; oz[k] = sxy;
        }
        *(float4*)&bh[0][r][4 * c] = oxx;
        *(float4*)&bh[1][r][4 * c] = oyy;
        *(float4*)&bh[2][r][4 * c] = oxy;
    }
    __syncthreads();

    // ---- vertical 7-tap + S write + hist: thread = (2 rows, 4 cols) ----
    int cg = t & 7, ro0 = (t >> 3) * 2;       // ro0 in 0..62
#pragma unroll
    for (int ch = 0; ch < 3; ch++) {
        float4 w[8];
#pragma unroll
        for (int j = 0; j < 8; j++) w[j] = *(float4*)&bh[ch][ro0 + j][4 * cg];
        float4 a0 = make_float4(0, 0, 0, 0), a1 = a0;
#pragma unroll
        for (int j = 0; j < 7; j++) {
            float gw = g.w[j];
            a0.x += gw * w[j].x;   a0.y += gw * w[j].y;
            a0.z += gw * w[j].z;   a0.w += gw * w[j].w;
            a1.x += gw * w[j+1].x; a1.y += gw * w[j+1].y;
            a1.z += gw * w[j+1].z; a1.w += gw * w[j+1].w;
        }
        float* sp = S + (size_t)(n * NCH + ch) * PIX;
        *(float4*)(sp + (size_t)(by + ro0)     * WW + bx + 4 * cg) = a0;
        *(float4*)(sp + (size_t)(by + ro0 + 1) * WW + bx + 4 * cg) = a1;
        hist_add(lh, myh, f2key(a0.x) >> 24); hist_add(lh, myh, f2key(a0.y) >> 24);
        hist_add(lh, myh, f2key(a0.z) >> 24); hist_add(lh, myh, f2key(a0.w) >> 24);
        hist_add(lh, myh, f2key(a1.x) >> 24); hist_add(lh, myh, f2key(a1.y) >> 24);
        hist_add(lh, myh, f2key(a1.z) >> 24); hist_add(lh, myh, f2key(a1.w) >> 24);
    }

    __syncthreads();
    if (threadIdx.x < 256) {
        unsigned v = 0;
#pragma unroll
        for (int c = 0; c < HCOPY; c++) v += lh[c * HSTRIDE + threadIdx.x];
        if (v) atomicAdd(&g_hist1p[((blockIdx.y * 64 + blockIdx.x) & (H1C - 1)) * 256 + threadIdx.x], v);
    }
}

// ---------------- Pass C: mid hist — 8-stream scan, 4096 bins [r13-proven] -
#define SCAN_BLOCKS 2048
#define NSTR 8
#define SLAB (TOT / 4 / NSTR)
__global__ __launch_bounds__(256) void hist_mid(const float* __restrict__ S) {
    __shared__ unsigned lh[4096];
    for (int i = threadIdx.x; i < 4096; i += 256) lh[i] = 0;
    __syncthreads();
    unsigned b1 = g_ctrl[0];
    const float4* S4 = (const float4*)S;
    long long stride = (long long)SCAN_BLOCKS * 256;
    for (long long i = (long long)blockIdx.x * 256 + threadIdx.x; i < SLAB; i += stride) {
        float4 v[NSTR];
#pragma unroll
        for (int s = 0; s < NSTR; s++) v[s] = S4[i + (long long)s * SLAB];
#pragma unroll
        for (int s = 0; s < NSTR; s++) {
            unsigned k0 = f2key(v[s].x), k1 = f2key(v[s].y),
                     k2 = f2key(v[s].z), k3 = f2key(v[s].w);
            if ((k0 >> 24) == b1) atomicAdd(&lh[(k0 >> 12) & 0xFFFu], 1u);
            if ((k1 >> 24) == b1) atomicAdd(&lh[(k1 >> 12) & 0xFFFu], 1u);
            if ((k2 >> 24) == b1) atomicAdd(&lh[(k2 >> 12) & 0xFFFu], 1u);
            if ((k3 >> 24) == b1) atomicAdd(&lh[(k3 >> 12) & 0xFFFu], 1u);
        }
    }
    __syncthreads();
    unsigned cpy = (blockIdx.x & (H23C - 1)) * 4096;
    for (int i = threadIdx.x; i < 4096; i += 256) {
        unsigned v = lh[i];
        if (v) atomicAdd(&g_hist2p[cpy + i], v);
    }
}

// ---------------- Pass D: low hist — 8-stream scan, 4096 bins [r13-proven] -
__global__ __launch_bounds__(256) void hist_low(const float* __restrict__ S) {
    __shared__ unsigned lh[4096];
    for (int i = threadIdx.x; i < 4096; i += 256) lh[i] = 0;
    __syncthreads();
    unsigned p2 = (g_ctrl[0] << 12) | g_ctrl[1];
    const float4* S4 = (const float4*)S;
    long long stride = (long long)SCAN_BLOCKS * 256;
    for (long long i = (long long)blockIdx.x * 256 + threadIdx.x; i < SLAB; i += stride) {
        float4 v[NSTR];
#pragma unroll
        for (int s = 0; s < NSTR; s++) v[s] = S4[i + (long long)s * SLAB];
#pragma unroll
        for (int s = 0; s < NSTR; s++) {
            unsigned k0 = f2key(v[s].x), k1 = f2key(v[s].y),
                     k2 = f2key(v[s].z), k3 = f2key(v[s].w);
            if ((k0 >> 12) == p2) atomicAdd(&lh[k0 & 0xFFFu], 1u);
            if ((k1 >> 12) == p2) atomicAdd(&lh[k1 & 0xFFFu], 1u);
            if ((k2 >> 12) == p2) atomicAdd(&lh[k2 & 0xFFFu], 1u);
            if ((k3 >> 12) == p2) atomicAdd(&lh[k3 & 0xFFFu], 1u);
        }
    }
    __syncthreads();
    unsigned cpy = (blockIdx.x & (H23C - 1)) * 4096;
    for (int i = threadIdx.x; i < 4096; i += 256) {
        unsigned v = lh[i];
        if (v) atomicAdd(&g_hist3p[cpy + i], v);
    }
}

// ---------------- bucket select over partial-copy histograms [r13-proven] --
__global__ __launch_bounds__(256) void select_k(int which) {
    __shared__ unsigned cnt[4096];
    __shared__ unsigned csum[256];
    int t = threadIdx.x;
    int nbins = (which == 0) ? 256 : 4096;
    if (which == 0) {
        unsigned s = 0;
        for (int c = 0; c < H1C; c++) s += g_hist1p[c * 256 + t];
        cnt[t] = s;
    } else {
        const unsigned* hp = (which == 1) ? g_hist2p : g_hist3p;
        for (int i = t; i < 4096; i += 256) {
            unsigned s = 0;
            for (int c = 0; c < H23C; c++) s += hp[c * 4096 + i];
            cnt[i] = s;
        }
    }
    __syncthreads();
    int per = nbins >> 8;
    unsigned s = 0;
    for (int j = 0; j < per; j++) s += cnt[t * per + j];
    csum[t] = s;
    __syncthreads();
    if (t == 0) {
        unsigned r = (which == 0) ? MED_RANK : (which == 1) ? g_ctrl[3] : g_ctrl[4];
        unsigned acc = 0; int c = 0;
        for (; c < 256; c++) { if (acc + csum[c] > r) break; acc += csum[c]; }
        int b = c * per;
        for (;; b++) { if (acc + cnt[b] > r) break; acc += cnt[b]; }
        if (which == 0)      { g_ctrl[0] = (unsigned)b; g_ctrl[3] = r - acc; }
        else if (which == 1) { g_ctrl[1] = (unsigned)b; g_ctrl[4] = r - acc; }
        else {
            g_ctrl[2] = (unsigned)b;
            unsigned key = (g_ctrl[0] << 24) | (g_ctrl[1] << 12) | (unsigned)b;
            unsigned bits = (key & 0x80000000u) ? (key ^ 0x80000000u) : ~key;
            g_med = __uint_as_float(bits);
        }
    }
}

// ---------------- Pass H: threshold + 7x7 NMS + mask — all-float4 [r13] ----
#define OX 64
#define OY 16
__global__ __launch_bounds__(256) void nms_kernel(const float* __restrict__ S,
                                                  float* __restrict__ out) {
    __shared__ float tin[22][72];
    __shared__ float hm[22][68];
    float med = g_med;
    int plane = blockIdx.z;
    int bx = blockIdx.x * OX, by = blockIdx.y * OY;
    const float* Sp = S + (size_t)plane * PIX;
    int t = threadIdx.x;

    for (int i = t; i < 22 * 18; i += 256) {
        int r = i / 18, cc = i % 18;
        int ghh = by + r - 3;
        int gc  = bx - 4 + cc * 4;
        float4 v = make_float4(-INFINITY, -INFINITY, -INFINITY, -INFINITY);
        if (ghh >= 0 && ghh < HH && gc >= 0 && gc < WW) {
            float4 s = *(const float4*)(Sp + (size_t)ghh * WW + gc);
            v.x = (s.x > med) ? s.x : 0.f;
            v.y = (s.y > med) ? s.y : 0.f;
            v.z = (s.z > med) ? s.z : 0.f;
            v.w = (s.w > med) ? s.w : 0.f;
        }
        *(float4*)&tin[r][cc * 4] = v;
    }
    __syncthreads();

    for (int i = t; i < 22 * 16; i += 256) {
        int r = i / 16, c = i % 16;
        float a0 = tin[r][4*c+1], a1 = tin[r][4*c+2], a2 = tin[r][4*c+3];
        float a3 = tin[r][4*c+4], a4 = tin[r][4*c+5], a5 = tin[r][4*c+6];
        float a6 = tin[r][4*c+7], a7 = tin[r][4*c+8], a8 = tin[r][4*c+9];
        float a9 = tin[r][4*c+10];
        float m03 = fmaxf(fmaxf(a0, a1), fmaxf(a2, a3));
        float m36 = fmaxf(fmaxf(a3, a4), fmaxf(a5, a6));
        float4 o;
        o.x = fmaxf(m03, fmaxf(fmaxf(a4, a5), a6));
        o.y = fmaxf(fmaxf(a1, a2), fmaxf(m36, a7));
        o.z = fmaxf(fmaxf(a2, a3), fmaxf(fmaxf(a4, m36), fmaxf(a7, a8)));
        o.w = fmaxf(m36, fmaxf(fmaxf(a7, a8), a9));
        *(float4*)&hm[r][4*c] = o;
    }
    __syncthreads();

    int cc = t & 15, ro = t >> 4;
    float4 m = *(const float4*)&hm[ro][4*cc];
#pragma unroll
    for (int d = 1; d < 7; d++) {
        float4 h = *(const float4*)&hm[ro + d][4*cc];
        m.x = fmaxf(m.x, h.x); m.y = fmaxf(m.y, h.y);
        m.z = fmaxf(m.z, h.z); m.w = fmaxf(m.w, h.w);
    }
    float4 c0 = *(const float4*)&tin[ro + 3][4*cc + 4];
    float4 o;
    o.x = (c0.x == m.x) ? c0.x : 0.f;
    o.y = (c0.y == m.y) ? c0.y : 0.f;
    o.z = (c0.z == m.z) ? c0.z : 0.f;
    o.w = (c0.w == m.w) ? c0.w : 0.f;
    *(float4*)(out + (size_t)plane * PIX + (size_t)(by + ro) * WW + bx + 4*cc) = o;
}

// ---------------- Launch ----------------
extern "C" void kernel_launch(void* const* d_in, const int* in_sizes, int n_in,
                              void* d_out, int out_size, void* d_ws, size_t ws_size,
                              hipStream_t stream) {
    const float* x = (const float*)d_in[0];
    float* O = (float*)d_out;                 // final output (scratch before nms)
    float* W = (float*)d_ws;                  // S buffer (TOT floats)

    GW g;
    {
        double gg[7], s = 0.0;
        for (int i = 0; i < 7; i++) { double r = i - 3.0; gg[i] = exp(-r * r / 50.0); s += gg[i]; }
        for (int i = 0; i < 7; i++) g.w[i] = (float)(gg[i] / s);
    }

    zero_state<<<256, 256, 0, stream>>>();
    // A+B fused: x -> S (in d_ws) + hist0; Bh lives in LDS only
    sobel_gauss_full<<<dim3(WW / TX, HH / TY, NIMG), 256, 0, stream>>>(x, W, g);
    select_k<<<1, 256, 0, stream>>>(0);
    hist_mid<<<SCAN_BLOCKS, 256, 0, stream>>>(W);
    select_k<<<1, 256, 0, stream>>>(1);
    hist_low<<<SCAN_BLOCKS, 256, 0, stream>>>(W);
    select_k<<<1, 256, 0, stream>>>(2);
    nms_kernel<<<dim3(WW / OX, HH / OY, PLANES), 256, 0, stream>>>(W, O);
}

// Round 15
// 513.810 us; speedup vs baseline: 7.2785x; 1.0070x over previous
//
#include <hip/hip_runtime.h>
#include <math.h>

#define HH 2048
#define WW 2048
#define NIMG 4
#define NCH 3
#define PLANES (NIMG*NCH)            // 12
#define PIX (HH*WW)                  // 4194304
#define TOT (PLANES*PIX)             // 50331648
#define W4 (WW/4)                    // 512
#define MED_RANK 25165823u           // floor(0.5*(TOT-1)), method='lower'

struct GW { float w[7]; };

// ---------------- module-global device state ----------------
// Cross-kernel visibility via kernel-boundary acquire/release (r4/r7-proven).
// Radix split: 8 (top) / 12 (mid) / 12 (low). Lessons: (r3/r8) count, don't
// place; (r9) zero every LDS copy; (r10) >=8 loads in flight; (r6) no hot
// global addresses; (r12) LDS same-address atomics serialize — replicate;
// (r14) per-value wave-ballot hist costs ~150 VALU ops/thread — RLE instead.
#define H1C 64
#define H23C 16
__device__ unsigned g_hist1p[H1C * 256];
__device__ unsigned g_hist2p[H23C * 4096];
__device__ unsigned g_hist3p[H23C * 4096];
__device__ unsigned g_ctrl[8];       // [0]=b1 [1]=b2 [2]=b3 [3]=rank2 [4]=rank3
__device__ float    g_med;

__global__ void zero_state() {       // 256 blocks x 256
    int t = blockIdx.x * 256 + threadIdx.x;   // < 65536
    if (t < H1C * 256) g_hist1p[t] = 0;
    g_hist2p[t] = 0;
    g_hist3p[t] = 0;
    if (t < 8) g_ctrl[t] = 0;
    if (t == 0) g_med = 0.f;
}

// ---------------- Median helpers ----------------
__device__ __forceinline__ unsigned f2key(float f) {
    unsigned b = __float_as_uint(f);
    return (b & 0x80000000u) ? ~b : (b | 0x80000000u);
}

#define HCOPY 8
#define HSTRIDE 257

// Run-length histogram accumulator: spatially-sequential values form bucket
// runs; one LDS atomic per run instead of per value (or per-wave ballots).
struct RLE {
    unsigned cur, cnt;
    __device__ __forceinline__ void init() { cur = 0xFFFFFFFFu; cnt = 0; }
    __device__ __forceinline__ void add(unsigned* myh, unsigned b) {
        if (b == cur) { cnt++; }
        else { if (cnt) atomicAdd(&myh[cur], cnt); cur = b; cnt = 1; }
    }
    __device__ __forceinline__ void flush(unsigned* myh) {
        if (cnt) atomicAdd(&myh[cur], cnt);
    }
};

// ---------------- Megakernel: Sobel + full 7x7 Gaussian + hist0 ------------
// Tile 64x32x3 per block; x and Bh tiles in LDS; S written once [r14-proven].
#define TX 32
#define TY 64
__global__ __launch_bounds__(256) void sobel_gauss_full(const float* __restrict__ x,
                                                        float* __restrict__ S, GW g) {
    __shared__ float xs[72][40];
    __shared__ float bh[3][70][36];
    __shared__ unsigned lh[HCOPY * HSTRIDE];
    for (int i = threadIdx.x; i < HCOPY * HSTRIDE; i += 256) lh[i] = 0;
    unsigned* myh = lh + (threadIdx.x & (HCOPY - 1)) * HSTRIDE;

    int bx = blockIdx.x * TX, by = blockIdx.y * TY;
    int n = blockIdx.z;
    const float* xp = x + (size_t)n * PIX;
    int t = threadIdx.x;

    // ---- stage x tile: 72 rows x 10 float4, zero-fill OOB ----
    for (int i = t; i < 72 * 10; i += 256) {
        int r = i / 10, cc = i % 10;
        int gr = by - 4 + r, gc = bx - 4 + cc * 4;
        float4 v = make_float4(0, 0, 0, 0);
        if (gr >= 0 && gr < HH && gc >= 0 && gc < WW)
            v = *(const float4*)(xp + (size_t)gr * WW + gc);
        *(float4*)&xs[r][cc * 4] = v;
    }
    __syncthreads();

    // ---- stage Bh: 70 rows x 8 col-groups, 3 channels [r14-proven] ----
    for (int i = t; i < 70 * 8; i += 256) {
        int r = i >> 3, c = i & 7;
        int imgrow = by - 3 + r;
        if (imgrow < 0 || imgrow >= HH) {
            float4 z = make_float4(0, 0, 0, 0);
            *(float4*)&bh[0][r][4 * c] = z;
            *(float4*)&bh[1][r][4 * c] = z;
            *(float4*)&bh[2][r][4 * c] = z;
            continue;
        }
        float r0[12], r1[12], r2[12];
#pragma unroll
        for (int b = 0; b < 3; b++) {
            float4 v0 = *(float4*)&xs[r][4 * c + 4 * b];
            float4 v1 = *(float4*)&xs[r + 1][4 * c + 4 * b];
            float4 v2 = *(float4*)&xs[r + 2][4 * c + 4 * b];
            r0[b*4+0]=v0.x; r0[b*4+1]=v0.y; r0[b*4+2]=v0.z; r0[b*4+3]=v0.w;
            r1[b*4+0]=v1.x; r1[b*4+1]=v1.y; r1[b*4+2]=v1.z; r1[b*4+3]=v1.w;
            r2[b*4+0]=v2.x; r2[b*4+1]=v2.y; r2[b*4+2]=v2.z; r2[b*4+3]=v2.w;
        }
        float pxx[10], pyy[10], pxy[10];
#pragma unroll
        for (int p = 0; p < 10; p++) {
            int ai = p + 1;
            int cg = bx + 4 * c - 3 + p;
            float Ix = (r0[ai+1] - r0[ai-1]) + 2.f*(r1[ai+1] - r1[ai-1]) + (r2[ai+1] - r2[ai-1]);
            float Iy = (r2[ai-1] - r0[ai-1]) + 2.f*(r2[ai]   - r0[ai])   + (r2[ai+1] - r0[ai+1]);
            bool ok = (cg >= 0 && cg < WW);
            pxx[p] = ok ? Ix * Ix : 0.f;
            pyy[p] = ok ? Iy * Iy : 0.f;
            pxy[p] = ok ? Ix * Iy : 0.f;
        }
        float4 oxx, oyy, oxy;
        float* ox = &oxx.x; float* oy = &oyy.x; float* oz = &oxy.x;
#pragma unroll
        for (int k = 0; k < 4; k++) {
            float sxx = 0.f, syy = 0.f, sxy = 0.f;
#pragma unroll
            for (int j = 0; j < 7; j++) {
                sxx += g.w[j] * pxx[k + j];
                syy += g.w[j] * pyy[k + j];
                sxy += g.w[j] * pxy[k + j];
            }
            ox[k] = sxx; oy[k] = syy; oz[k] = sxy;
        }
        *(float4*)&bh[0][r][4 * c] = oxx;
        *(float4*)&bh[1][r][4 * c] = oyy;
        *(float4*)&bh[2][r][4 * c] = oxy;
    }
    __syncthreads();

    // ---- vertical 7-tap + S write + RLE hist ----
    int cg = t & 7, ro0 = (t >> 3) * 2;
    RLE rle; rle.init();
#pragma unroll
    for (int ch = 0; ch < 3; ch++) {
        float4 w[8];
#pragma unroll
        for (int j = 0; j < 8; j++) w[j] = *(float4*)&bh[ch][ro0 + j][4 * cg];
        float4 a0 = make_float4(0, 0, 0, 0), a1 = a0;
#pragma unroll
        for (int j = 0; j < 7; j++) {
            float gw = g.w[j];
            a0.x += gw * w[j].x;   a0.y += gw * w[j].y;
            a0.z += gw * w[j].z;   a0.w += gw * w[j].w;
            a1.x += gw * w[j+1].x; a1.y += gw * w[j+1].y;
            a1.z += gw * w[j+1].z; a1.w += gw * w[j+1].w;
        }
        float* sp = S + (size_t)(n * NCH + ch) * PIX;
        *(float4*)(sp + (size_t)(by + ro0)     * WW + bx + 4 * cg) = a0;
        *(float4*)(sp + (size_t)(by + ro0 + 1) * WW + bx + 4 * cg) = a1;
        rle.add(myh, f2key(a0.x) >> 24); rle.add(myh, f2key(a0.y) >> 24);
        rle.add(myh, f2key(a0.z) >> 24); rle.add(myh, f2key(a0.w) >> 24);
        rle.add(myh, f2key(a1.x) >> 24); rle.add(myh, f2key(a1.y) >> 24);
        rle.add(myh, f2key(a1.z) >> 24); rle.add(myh, f2key(a1.w) >> 24);
    }
    rle.flush(myh);

    __syncthreads();
    if (threadIdx.x < 256) {
        unsigned v = 0;
#pragma unroll
        for (int c = 0; c < HCOPY; c++) v += lh[c * HSTRIDE + threadIdx.x];
        if (v) atomicAdd(&g_hist1p[((blockIdx.y * 64 + blockIdx.x) & (H1C - 1)) * 256 + threadIdx.x], v);
    }
}

// ---------------- Pass C: mid hist — fully-unrolled 24-load scan -----------
#define SCAN_BLOCKS 2048
#define NSTR 8
#define SLAB (TOT / 4 / NSTR)        // 1572864 float4 per slab; 3 iters/thread
__global__ __launch_bounds__(256) void hist_mid(const float* __restrict__ S) {
    __shared__ unsigned lh[4096];
    for (int i = threadIdx.x; i < 4096; i += 256) lh[i] = 0;
    __syncthreads();
    unsigned b1 = g_ctrl[0];
    const float4* S4 = (const float4*)S;
    long long i0 = (long long)blockIdx.x * 256 + threadIdx.x;
    const long long STRIDE = (long long)SCAN_BLOCKS * 256;  // 524288
    float4 v[3][NSTR];                 // 24 loads in flight
#pragma unroll
    for (int it = 0; it < 3; it++)
#pragma unroll
        for (int s = 0; s < NSTR; s++)
            v[it][s] = S4[i0 + it * STRIDE + (long long)s * SLAB];
#pragma unroll
    for (int it = 0; it < 3; it++)
#pragma unroll
        for (int s = 0; s < NSTR; s++) {
            unsigned k0 = f2key(v[it][s].x), k1 = f2key(v[it][s].y),
                     k2 = f2key(v[it][s].z), k3 = f2key(v[it][s].w);
            if ((k0 >> 24) == b1) atomicAdd(&lh[(k0 >> 12) & 0xFFFu], 1u);
            if ((k1 >> 24) == b1) atomicAdd(&lh[(k1 >> 12) & 0xFFFu], 1u);
            if ((k2 >> 24) == b1) atomicAdd(&lh[(k2 >> 12) & 0xFFFu], 1u);
            if ((k3 >> 24) == b1) atomicAdd(&lh[(k3 >> 12) & 0xFFFu], 1u);
        }
    __syncthreads();
    unsigned cpy = (blockIdx.x & (H23C - 1)) * 4096;
    for (int i = threadIdx.x; i < 4096; i += 256) {
        unsigned vv = lh[i];
        if (vv) atomicAdd(&g_hist2p[cpy + i], vv);
    }
}

// ---------------- Pass D: low hist — fully-unrolled 24-load scan -----------
__global__ __launch_bounds__(256) void hist_low(const float* __restrict__ S) {
    __shared__ unsigned lh[4096];
    for (int i = threadIdx.x; i < 4096; i += 256) lh[i] = 0;
    __syncthreads();
    unsigned p2 = (g_ctrl[0] << 12) | g_ctrl[1];
    const float4* S4 = (const float4*)S;
    long long i0 = (long long)blockIdx.x * 256 + threadIdx.x;
    const long long STRIDE = (long long)SCAN_BLOCKS * 256;
    float4 v[3][NSTR];
#pragma unroll
    for (int it = 0; it < 3; it++)
#pragma unroll
        for (int s = 0; s < NSTR; s++)
            v[it][s] = S4[i0 + it * STRIDE + (long long)s * SLAB];
#pragma unroll
    for (int it = 0; it < 3; it++)
#pragma unroll
        for (int s = 0; s < NSTR; s++) {
            unsigned k0 = f2key(v[it][s].x), k1 = f2key(v[it][s].y),
                     k2 = f2key(v[it][s].z), k3 = f2key(v[it][s].w);
            if ((k0 >> 12) == p2) atomicAdd(&lh[k0 & 0xFFFu], 1u);
            if ((k1 >> 12) == p2) atomicAdd(&lh[k1 & 0xFFFu], 1u);
            if ((k2 >> 12) == p2) atomicAdd(&lh[k2 & 0xFFFu], 1u);
            if ((k3 >> 12) == p2) atomicAdd(&lh[k3 & 0xFFFu], 1u);
        }
    __syncthreads();
    unsigned cpy = (blockIdx.x & (H23C - 1)) * 4096;
    for (int i = threadIdx.x; i < 4096; i += 256) {
        unsigned vv = lh[i];
        if (vv) atomicAdd(&g_hist3p[cpy + i], vv);
    }
}

// ---------------- bucket select over partial-copy histograms [r13-proven] --
__global__ __launch_bounds__(256) void select_k(int which) {
    __shared__ unsigned cnt[4096];
    __shared__ unsigned csum[256];
    int t = threadIdx.x;
    int nbins = (which == 0) ? 256 : 4096;
    if (which == 0) {
        unsigned s = 0;
        for (int c = 0; c < H1C; c++) s += g_hist1p[c * 256 + t];
        cnt[t] = s;
    } else {
        const unsigned* hp = (which == 1) ? g_hist2p : g_hist3p;
        for (int i = t; i < 4096; i += 256) {
            unsigned s = 0;
            for (int c = 0; c < H23C; c++) s += hp[c * 4096 + i];
            cnt[i] = s;
        }
    }
    __syncthreads();
    int per = nbins >> 8;
    unsigned s = 0;
    for (int j = 0; j < per; j++) s += cnt[t * per + j];
    csum[t] = s;
    __syncthreads();
    if (t == 0) {
        unsigned r = (which == 0) ? MED_RANK : (which == 1) ? g_ctrl[3] : g_ctrl[4];
        unsigned acc = 0; int c = 0;
        for (; c < 256; c++) { if (acc + csum[c] > r) break; acc += csum[c]; }
        int b = c * per;
        for (;; b++) { if (acc + cnt[b] > r) break; acc += cnt[b]; }
        if (which == 0)      { g_ctrl[0] = (unsigned)b; g_ctrl[3] = r - acc; }
        else if (which == 1) { g_ctrl[1] = (unsigned)b; g_ctrl[4] = r - acc; }
        else {
            g_ctrl[2] = (unsigned)b;
            unsigned key = (g_ctrl[0] << 24) | (g_ctrl[1] << 12) | (unsigned)b;
            unsigned bits = (key & 0x80000000u) ? (key ^ 0x80000000u) : ~key;
            g_med = __uint_as_float(bits);
        }
    }
}

// ---------------- Pass H: threshold + 7x7 NMS + mask — all-float4 [r13] ----
#define OX 64
#define OY 16
__global__ __launch_bounds__(256) void nms_kernel(const float* __restrict__ S,
                                                  float* __restrict__ out) {
    __shared__ float tin[22][72];
    __shared__ float hm[22][68];
    float med = g_med;
    int plane = blockIdx.z;
    int bx = blockIdx.x * OX, by = blockIdx.y * OY;
    const float* Sp = S + (size_t)plane * PIX;
    int t = threadIdx.x;

    for (int i = t; i < 22 * 18; i += 256) {
        int r = i / 18, cc = i % 18;
        int ghh = by + r - 3;
        int gc  = bx - 4 + cc * 4;
        float4 v = make_float4(-INFINITY, -INFINITY, -INFINITY, -INFINITY);
        if (ghh >= 0 && ghh < HH && gc >= 0 && gc < WW) {
            float4 s = *(const float4*)(Sp + (size_t)ghh * WW + gc);
            v.x = (s.x > med) ? s.x : 0.f;
            v.y = (s.y > med) ? s.y : 0.f;
            v.z = (s.z > med) ? s.z : 0.f;
            v.w = (s.w > med) ? s.w : 0.f;
        }
        *(float4*)&tin[r][cc * 4] = v;
    }
    __syncthreads();

    for (int i = t; i < 22 * 16; i += 256) {
        int r = i / 16, c = i % 16;
        float a0 = tin[r][4*c+1], a1 = tin[r][4*c+2], a2 = tin[r][4*c+3];
        float a3 = tin[r][4*c+4], a4 = tin[r][4*c+5], a5 = tin[r][4*c+6];
        float a6 = tin[r][4*c+7], a7 = tin[r][4*c+8], a8 = tin[r][4*c+9];
        float a9 = tin[r][4*c+10];
        float m03 = fmaxf(fmaxf(a0, a1), fmaxf(a2, a3));
        float m36 = fmaxf(fmaxf(a3, a4), fmaxf(a5, a6));
        float4 o;
        o.x = fmaxf(m03, fmaxf(fmaxf(a4, a5), a6));
        o.y = fmaxf(fmaxf(a1, a2), fmaxf(m36, a7));
        o.z = fmaxf(fmaxf(a2, a3), fmaxf(fmaxf(a4, m36), fmaxf(a7, a8)));
        o.w = fmaxf(m36, fmaxf(fmaxf(a7, a8), a9));
        *(float4*)&hm[r][4*c] = o;
    }
    __syncthreads();

    int cc = t & 15, ro = t >> 4;
    float4 m = *(const float4*)&hm[ro][4*cc];
#pragma unroll
    for (int d = 1; d < 7; d++) {
        float4 h = *(const float4*)&hm[ro + d][4*cc];
        m.x = fmaxf(m.x, h.x); m.y = fmaxf(m.y, h.y);
        m.z = fmaxf(m.z, h.z); m.w = fmaxf(m.w, h.w);
    }
    float4 c0 = *(const float4*)&tin[ro + 3][4*cc + 4];
    float4 o;
    o.x = (c0.x == m.x) ? c0.x : 0.f;
    o.y = (c0.y == m.y) ? c0.y : 0.f;
    o.z = (c0.z == m.z) ? c0.z : 0.f;
    o.w = (c0.w == m.w) ? c0.w : 0.f;
    *(float4*)(out + (size_t)plane * PIX + (size_t)(by + ro) * WW + bx + 4*cc) = o;
}

// ---------------- Launch ----------------
extern "C" void kernel_launch(void* const* d_in, const int* in_sizes, int n_in,
                              void* d_out, int out_size, void* d_ws, size_t ws_size,
                              hipStream_t stream) {
    const float* x = (const float*)d_in[0];
    float* O = (float*)d_out;
    float* W = (float*)d_ws;

    GW g;
    {
        double gg[7], s = 0.0;
        for (int i = 0; i < 7; i++) { double r = i - 3.0; gg[i] = exp(-r * r / 50.0); s += gg[i]; }
        for (int i = 0; i < 7; i++) g.w[i] = (float)(gg[i] / s);
    }

    zero_state<<<256, 256, 0, stream>>>();
    sobel_gauss_full<<<dim3(WW / TX, HH / TY, NIMG), 256, 0, stream>>>(x, W, g);
    select_k<<<1, 256, 0, stream>>>(0);
    hist_mid<<<SCAN_BLOCKS, 256, 0, stream>>>(W);
    select_k<<<1, 256, 0, stream>>>(1);
    hist_low<<<SCAN_BLOCKS, 256, 0, stream>>>(W);
    select_k<<<1, 256, 0, stream>>>(2);
    nms_kernel<<<dim3(WW / OX, HH / OY, PLANES), 256, 0, stream>>>(W, O);
}